// Round 1
// baseline (337.045 us; speedup 1.0000x reference)
//
#include <hip/hip_runtime.h>
#include <stdint.h>

// ---------------------------------------------------------------------------
// MultiHeadAttention B=4 T=2048 C=1024 H=16 D=64  (fp32 in/out, causal)
// Pipeline: cvt(bf16) -> GEMM(QKV) -> transpose(V) -> flash-attn -> GEMM(proj)+bias
// ---------------------------------------------------------------------------

typedef unsigned short u16;
typedef __attribute__((ext_vector_type(8))) short   s16x8;
typedef __attribute__((ext_vector_type(4))) float   f32x4;

// --- helpers ---------------------------------------------------------------

__device__ __forceinline__ u16 f2b(float f) {  // f32 -> bf16 RNE
  union { float f; uint32_t u; } v; v.f = f;
  uint32_t r = v.u + 0x7FFFu + ((v.u >> 16) & 1u);
  return (u16)(r >> 16);
}

// v_mfma_f32_16x16x32_bf16 via inline asm (robust to builtin operand-type drift).
// A frag: lane holds A[m=l&15][k: 8 contiguous]; B frag: lane holds B^T[n=l&15][k: 8 contiguous]
// C/D: row=(l>>4)*4+reg, col=l&15   [verified layout, learn_hip m89/m91]
__device__ __forceinline__ f32x4 mfma_bf16(s16x8 a, s16x8 b, f32x4 c) {
  asm("v_mfma_f32_16x16x32_bf16 %0, %1, %2, %0" : "+v"(c) : "v"(a), "v"(b));
  return c;
}

// async global->LDS, 16B per lane. LDS dest is wave-uniform base + lane*16.
__device__ __forceinline__ void gload_lds16(const void* g, void* l) {
  __builtin_amdgcn_global_load_lds(
      (__attribute__((address_space(1))) void*)(uintptr_t)g,
      (__attribute__((address_space(3))) void*)(uint32_t)(uintptr_t)l,
      16, 0, 0);
}

// --- conversion kernels ------------------------------------------------------

// straight f32 -> bf16, 8 elems/thread (also used for Wp: layout is already [N][K])
__global__ void cvt_f32_bf16_kernel(const float* __restrict__ in, u16* __restrict__ out) {
  size_t i = (size_t)blockIdx.x * 256 + threadIdx.x;
  const f32x4* p = (const f32x4*)(in + i * 8);
  f32x4 a = p[0], b = p[1];
  s16x8 o;
  o[0]=(short)f2b(a[0]); o[1]=(short)f2b(a[1]); o[2]=(short)f2b(a[2]); o[3]=(short)f2b(a[3]);
  o[4]=(short)f2b(b[0]); o[5]=(short)f2b(b[1]); o[6]=(short)f2b(b[2]); o[7]=(short)f2b(b[3]);
  *(s16x8*)(out + i * 8) = o;
}

// Wq/Wk/Wv [H,C,D] f32 -> wqkvb [3*H*D][C] bf16  (B^T layout for the GEMM)
__global__ void cvt_wqkv_kernel(const float* __restrict__ Wq, const float* __restrict__ Wk,
                                const float* __restrict__ Wv, u16* __restrict__ out) {
  int idx = blockIdx.x * 256 + threadIdx.x;       // 0 .. 3*1024*1024-1
  int sel = idx >> 20;
  int rem = idx & 1048575;
  int n = rem >> 10, c = rem & 1023;
  int h = n >> 6, d = n & 63;
  const float* W = (sel == 0) ? Wq : ((sel == 1) ? Wk : Wv);
  out[idx] = f2b(W[h * 65536 + c * 64 + d]);
}

// --- GEMM: C[M][N] = A[M][K] * B[N][K]^T  (bf16 in, 128x128 tile, BK=64) ----

template <bool OUT_F32, bool BIAS>
__global__ __launch_bounds__(256) void gemm_bt_kernel(
    const u16* __restrict__ A, const u16* __restrict__ B, void* __restrict__ Cout,
    const float* __restrict__ bias, int K, int ldc)
{
  __shared__ __attribute__((aligned(16))) u16 As[128 * 64];
  __shared__ __attribute__((aligned(16))) u16 Bs[128 * 64];

  const int tid  = threadIdx.x;
  const int lane = tid & 63;
  const int w    = tid >> 6;
  const int wm   = w >> 1, wn = w & 1;          // 2x2 wave grid, 64x64 each
  const int g    = lane >> 4;
  const int li   = lane & 15;
  const size_t bm = (size_t)blockIdx.x * 128;
  const size_t bn = (size_t)blockIdx.y * 128;

  f32x4 acc[4][4] = {};

  const int kIters = K >> 6;
  for (int kt = 0; kt < kIters; ++kt) {
    const int kb = kt * 64;
#pragma unroll
    for (int i = 0; i < 4; ++i) {
      // chunk c covers LDS bytes [c*16, c*16+16): row = c>>3, lds slot = c&7
      // linear LDS dest + inverse-swizzled SOURCE slot (involution: slot ^ (row&7))
      int c = i * 256 + tid;
      int row = c >> 3, sl = c & 7;
      int ss = sl ^ (row & 7);
      gload_lds16(A + (bm + row) * K + kb + ss * 8, &As[c * 8]);
      gload_lds16(B + (bn + row) * K + kb + ss * 8, &Bs[c * 8]);
    }
    __syncthreads();   // compiler drains vmcnt before s_barrier
#pragma unroll
    for (int ks = 0; ks < 2; ++ks) {
      s16x8 af[4], bfr[4];
#pragma unroll
      for (int f = 0; f < 4; ++f) {
        int ra = wm * 64 + f * 16 + li;
        int sa = (ks * 4 + g) ^ (ra & 7);
        af[f] = *(const s16x8*)&As[ra * 64 + sa * 8];
        int rb = wn * 64 + f * 16 + li;
        int sb = (ks * 4 + g) ^ (rb & 7);
        bfr[f] = *(const s16x8*)&Bs[rb * 64 + sb * 8];
      }
#pragma unroll
      for (int mi = 0; mi < 4; ++mi)
#pragma unroll
        for (int ni = 0; ni < 4; ++ni)
          acc[mi][ni] = mfma_bf16(af[mi], bfr[ni], acc[mi][ni]);
    }
    __syncthreads();
  }

#pragma unroll
  for (int ni = 0; ni < 4; ++ni) {
    size_t col = bn + wn * 64 + ni * 16 + li;
    float bv = BIAS ? bias[col] : 0.f;
#pragma unroll
    for (int mi = 0; mi < 4; ++mi) {
#pragma unroll
      for (int r = 0; r < 4; ++r) {
        size_t row = bm + wm * 64 + mi * 16 + g * 4 + r;
        if constexpr (OUT_F32) ((float*)Cout)[row * ldc + col] = acc[mi][ni][r] + bv;
        else                   ((u16*)Cout)[row * ldc + col] = f2b(acc[mi][ni][r]);
      }
    }
  }
}

// --- V transpose: qkv v-section [t][h*64+d] -> vT[bh][d][t] ------------------

__global__ __launch_bounds__(256) void transpose_v_kernel(const u16* __restrict__ qkv,
                                                          u16* __restrict__ vT) {
  __shared__ __attribute__((aligned(16))) u16 ts[64][72];
  const int bh = blockIdx.y;
  const int b = bh >> 4, h = bh & 15;
  const int t0 = blockIdx.x * 64;
  const u16* src = qkv + (size_t)(b * 2048 + t0) * 3072 + 2048 + h * 64;
#pragma unroll
  for (int i = 0; i < 2; ++i) {
    int c = i * 256 + threadIdx.x;
    int row = c >> 3, sl = c & 7;
    *(s16x8*)&ts[row][sl * 8] = *(const s16x8*)&src[(size_t)row * 3072 + sl * 8];
  }
  __syncthreads();
  u16* dst = vT + (size_t)bh * 64 * 2048 + t0;
#pragma unroll
  for (int i = 0; i < 2; ++i) {
    int c = i * 256 + threadIdx.x;
    int drow = c >> 3, sl = c & 7;
    s16x8 o;
#pragma unroll
    for (int j = 0; j < 8; ++j) o[j] = (short)ts[sl * 8 + j][drow];
    *(s16x8*)&dst[(size_t)drow * 2048 + sl * 8] = o;
  }
}

// --- flash attention (causal), QBLK=128 (4 waves x 32 rows), KVBLK=64 -------

__global__ __launch_bounds__(256) void attn_kernel(const u16* __restrict__ qkv,
                                                   const u16* __restrict__ vT,
                                                   u16* __restrict__ out) {
  __shared__ __attribute__((aligned(16))) u16 Ks[64 * 64];
  __shared__ __attribute__((aligned(16))) u16 Vs[64 * 64];     // V^T tile: [d][j]
  __shared__ __attribute__((aligned(16))) u16 Ps[4][32 * 72];  // per-wave P, pad->72

  const int qt = (gridDim.x - 1) - blockIdx.x;   // heavy tiles first
  const int bh = blockIdx.y;
  const int b = bh >> 4, h = bh & 15;
  const int lane = threadIdx.x & 63;
  const int w = threadIdx.x >> 6;
  const int g = lane >> 4;
  const int li = lane & 15;
  const int q0 = qt * 128;
  const int wq0 = q0 + w * 32;

  const u16* qbase = qkv + (size_t)(b * 2048 + wq0) * 3072 + h * 64;
  const u16* kbase = qkv + (size_t)(b * 2048) * 3072 + 1024 + h * 64;
  const u16* vtb   = vT + (size_t)bh * 64 * 2048;

  // Q fragments held in registers for the whole block
  s16x8 qf[2][2];
#pragma unroll
  for (int fm = 0; fm < 2; ++fm)
#pragma unroll
    for (int ks = 0; ks < 2; ++ks)
      qf[fm][ks] = *(const s16x8*)&qbase[(size_t)(fm * 16 + li) * 3072 + ks * 32 + g * 8];

  f32x4 oacc[2][4] = {};
  float mrow[2][4], lrow[2][4];
#pragma unroll
  for (int fm = 0; fm < 2; ++fm)
#pragma unroll
    for (int r = 0; r < 4; ++r) { mrow[fm][r] = -1e30f; lrow[fm][r] = 0.f; }

  const float cexp = 0.18033688011112042f;  // (1/sqrt(64)) * log2(e)
  const int nkv = (qt + 1) * 2;

  for (int t = 0; t < nkv; ++t) {
    const int j0 = t * 64;
#pragma unroll
    for (int i = 0; i < 2; ++i) {
      int c = i * 256 + threadIdx.x;
      int row = c >> 3, sl = c & 7, ss = sl ^ (row & 7);
      gload_lds16(kbase + (size_t)(j0 + row) * 3072 + ss * 8, &Ks[c * 8]);
      gload_lds16(vtb + (size_t)row * 2048 + j0 + ss * 8, &Vs[c * 8]);
    }
    __syncthreads();

    if (j0 <= wq0 + 31) {   // causal tile-skip per wave (barriers stay uniform)
      // S = Q K^T
      f32x4 sfr[2][4] = {};
#pragma unroll
      for (int ks = 0; ks < 2; ++ks) {
        s16x8 kf[4];
#pragma unroll
        for (int fj = 0; fj < 4; ++fj) {
          int rk = fj * 16 + li;
          int ssl = (ks * 4 + g) ^ (rk & 7);
          kf[fj] = *(const s16x8*)&Ks[rk * 64 + ssl * 8];
        }
#pragma unroll
        for (int fm = 0; fm < 2; ++fm)
#pragma unroll
          for (int fj = 0; fj < 4; ++fj)
            sfr[fm][fj] = mfma_bf16(qf[fm][ks], kf[fj], sfr[fm][fj]);
      }
      // causal mask (only diagonal tiles hit this)
      if (j0 + 63 > wq0) {
#pragma unroll
        for (int fm = 0; fm < 2; ++fm)
#pragma unroll
          for (int fj = 0; fj < 4; ++fj)
#pragma unroll
            for (int r = 0; r < 4; ++r) {
              int ii = wq0 + fm * 16 + g * 4 + r;
              int jj = j0 + fj * 16 + li;
              if (jj > ii) sfr[fm][fj][r] = -1e30f;
            }
      }
      // online softmax (row = fm*16 + g*4 + r; reduce over 16-lane col group)
#pragma unroll
      for (int fm = 0; fm < 2; ++fm) {
#pragma unroll
        for (int r = 0; r < 4; ++r) {
          float mx = fmaxf(fmaxf(sfr[fm][0][r], sfr[fm][1][r]),
                           fmaxf(sfr[fm][2][r], sfr[fm][3][r]));
          mx = fmaxf(mx, __shfl_xor(mx, 1));
          mx = fmaxf(mx, __shfl_xor(mx, 2));
          mx = fmaxf(mx, __shfl_xor(mx, 4));
          mx = fmaxf(mx, __shfl_xor(mx, 8));
          float mnew = fmaxf(mrow[fm][r], mx);
          float sc = exp2f((mrow[fm][r] - mnew) * cexp);
          mrow[fm][r] = mnew;
          lrow[fm][r] *= sc;
#pragma unroll
          for (int fd = 0; fd < 4; ++fd) oacc[fm][fd][r] *= sc;
          float rs = 0.f;
#pragma unroll
          for (int fj = 0; fj < 4; ++fj) {
            float p = exp2f((sfr[fm][fj][r] - mnew) * cexp);
            sfr[fm][fj][r] = p;
            rs += p;
          }
          rs += __shfl_xor(rs, 1);
          rs += __shfl_xor(rs, 2);
          rs += __shfl_xor(rs, 4);
          rs += __shfl_xor(rs, 8);
          lrow[fm][r] += rs;
        }
      }
      // P -> LDS (bf16), then PV
      u16* pl = Ps[w];
#pragma unroll
      for (int fm = 0; fm < 2; ++fm)
#pragma unroll
        for (int fj = 0; fj < 4; ++fj)
#pragma unroll
          for (int r = 0; r < 4; ++r)
            pl[(fm * 16 + g * 4 + r) * 72 + fj * 16 + li] = f2b(sfr[fm][fj][r]);
#pragma unroll
      for (int ks = 0; ks < 2; ++ks) {
        s16x8 pf[2], vf[4];
#pragma unroll
        for (int fm = 0; fm < 2; ++fm)
          pf[fm] = *(const s16x8*)&pl[(fm * 16 + li) * 72 + ks * 32 + g * 8];
#pragma unroll
        for (int fd = 0; fd < 4; ++fd) {
          int rv = fd * 16 + li;
          int ssl = (ks * 4 + g) ^ (rv & 7);
          vf[fd] = *(const s16x8*)&Vs[rv * 64 + ssl * 8];
        }
#pragma unroll
        for (int fm = 0; fm < 2; ++fm)
#pragma unroll
          for (int fd = 0; fd < 4; ++fd)
            oacc[fm][fd] = mfma_bf16(pf[fm], vf[fd], oacc[fm][fd]);
      }
    }
    __syncthreads();
  }

  // epilogue: O /= l, write bf16 [8192][1024] at cols h*64..h*64+63
  u16* ob = out + (size_t)(b * 2048 + wq0) * 1024 + h * 64;
#pragma unroll
  for (int fm = 0; fm < 2; ++fm) {
#pragma unroll
    for (int r = 0; r < 4; ++r) {
      float inv = 1.f / lrow[fm][r];
#pragma unroll
      for (int fd = 0; fd < 4; ++fd)
        ob[(size_t)(fm * 16 + g * 4 + r) * 1024 + fd * 16 + li] = f2b(oacc[fm][fd][r] * inv);
    }
  }
}

// --- launch ------------------------------------------------------------------

extern "C" void kernel_launch(void* const* d_in, const int* in_sizes, int n_in,
                              void* d_out, int out_size, void* d_ws, size_t ws_size,
                              hipStream_t stream) {
  const float* x  = (const float*)d_in[0];
  const float* Wq = (const float*)d_in[1];
  const float* Wk = (const float*)d_in[2];
  const float* Wv = (const float*)d_in[3];
  const float* Wp = (const float*)d_in[4];
  const float* bp = (const float*)d_in[5];
  (void)in_sizes; (void)n_in; (void)out_size; (void)ws_size;

  char* ws = (char*)d_ws;
  u16* xb    = (u16*)(ws);                   // [8192][1024]  16 MB
  u16* wqkvb = (u16*)(ws + 16777216);        // [3072][1024]   6 MB
  u16* wpb   = (u16*)(ws + 23068672);        // [1024][1024]   2 MB
  u16* qkv   = (u16*)(ws + 25165824);        // [8192][3072]  48 MB
  u16* vT    = (u16*)(ws + 75497472);        // [64][64][2048] 16 MB
  u16* ao    = (u16*)(ws + 92274688);        // [8192][1024]  16 MB

  cvt_f32_bf16_kernel<<<4096, 256, 0, stream>>>(x, xb);                  // 8.4M elems
  cvt_wqkv_kernel<<<12288, 256, 0, stream>>>(Wq, Wk, Wv, wqkvb);         // 3M elems
  cvt_f32_bf16_kernel<<<512, 256, 0, stream>>>(Wp, wpb);                 // 1M elems

  gemm_bt_kernel<false, false><<<dim3(64, 24), 256, 0, stream>>>(
      xb, wqkvb, (void*)qkv, nullptr, 1024, 3072);

  transpose_v_kernel<<<dim3(32, 64), 256, 0, stream>>>(qkv, vT);

  attn_kernel<<<dim3(16, 64), 256, 0, stream>>>(qkv, vT, ao);

  gemm_bt_kernel<true, true><<<dim3(64, 8), 256, 0, stream>>>(
      ao, wpb, d_out, bp, 1024, 1024);
}

// Round 2
// 218.915 us; speedup vs baseline: 1.5396x; 1.5396x over previous
//
#include <hip/hip_runtime.h>
#include <stdint.h>

// ---------------------------------------------------------------------------
// MultiHeadAttention B=4 T=2048 C=1024 H=16 D=64  (fp32 in/out, causal)
// Pipeline: cvt(bf16) -> GEMM(QKV) -> transpose(V) -> flash-attn -> GEMM(proj)+bias
// ---------------------------------------------------------------------------

typedef unsigned short u16;
typedef __attribute__((ext_vector_type(8))) short   s16x8;
typedef __attribute__((ext_vector_type(4))) float   f32x4;

// --- helpers ---------------------------------------------------------------

__device__ __forceinline__ u16 f2b(float f) {  // f32 -> bf16 RNE
  union { float f; uint32_t u; } v; v.f = f;
  uint32_t r = v.u + 0x7FFFu + ((v.u >> 16) & 1u);
  return (u16)(r >> 16);
}

// v_mfma_f32_16x16x32_bf16 via inline asm.
// A frag: lane holds A[m=l&15][k: 8 contig at (ks*4+g)*8]; B frag: B^T[n=l&15][k contig]
// C/D: row=(l>>4)*4+reg, col=l&15   [verified layout, learn_hip m89/m91]
__device__ __forceinline__ f32x4 mfma_bf16(s16x8 a, s16x8 b, f32x4 c) {
  asm("v_mfma_f32_16x16x32_bf16 %0, %1, %2, %0" : "+v"(c) : "v"(a), "v"(b));
  return c;
}

// async global->LDS, 16B per lane. LDS dest is wave-uniform base + lane*16.
__device__ __forceinline__ void gload_lds16(const void* g, void* l) {
  __builtin_amdgcn_global_load_lds(
      (__attribute__((address_space(1))) void*)(uintptr_t)g,
      (__attribute__((address_space(3))) void*)(uint32_t)(uintptr_t)l,
      16, 0, 0);
}

// --- conversion kernels ------------------------------------------------------

__global__ void cvt_f32_bf16_kernel(const float* __restrict__ in, u16* __restrict__ out) {
  size_t i = (size_t)blockIdx.x * 256 + threadIdx.x;
  const f32x4* p = (const f32x4*)(in + i * 8);
  f32x4 a = p[0], b = p[1];
  s16x8 o;
  o[0]=(short)f2b(a[0]); o[1]=(short)f2b(a[1]); o[2]=(short)f2b(a[2]); o[3]=(short)f2b(a[3]);
  o[4]=(short)f2b(b[0]); o[5]=(short)f2b(b[1]); o[6]=(short)f2b(b[2]); o[7]=(short)f2b(b[3]);
  *(s16x8*)(out + i * 8) = o;
}

// Wq/Wk/Wv [H,C,D] f32 -> wqkvb [3*H*D][C] bf16  (B^T layout for the GEMM)
__global__ void cvt_wqkv_kernel(const float* __restrict__ Wq, const float* __restrict__ Wk,
                                const float* __restrict__ Wv, u16* __restrict__ out) {
  int idx = blockIdx.x * 256 + threadIdx.x;
  int sel = idx >> 20;
  int rem = idx & 1048575;
  int n = rem >> 10, c = rem & 1023;
  int h = n >> 6, d = n & 63;
  const float* W = (sel == 0) ? Wq : ((sel == 1) ? Wk : Wv);
  out[idx] = f2b(W[h * 65536 + c * 64 + d]);
}

// --- GEMM: C[M][N] = A[M][K] * B[N][K]^T  (bf16 in, 128x128 tile, BK=64) ----

template <bool OUT_F32, bool BIAS>
__global__ __launch_bounds__(256) void gemm_bt_kernel(
    const u16* __restrict__ A, const u16* __restrict__ B, void* __restrict__ Cout,
    const float* __restrict__ bias, int K, int ldc)
{
  __shared__ __attribute__((aligned(16))) u16 As[128 * 64];
  __shared__ __attribute__((aligned(16))) u16 Bs[128 * 64];

  const int tid  = threadIdx.x;
  const int lane = tid & 63;
  const int w    = tid >> 6;
  const int wm   = w >> 1, wn = w & 1;
  const int g    = lane >> 4;
  const int li   = lane & 15;
  const size_t bm = (size_t)blockIdx.x * 128;
  const size_t bn = (size_t)blockIdx.y * 128;

  f32x4 acc[4][4] = {};

  const int kIters = K >> 6;
  for (int kt = 0; kt < kIters; ++kt) {
    const int kb = kt * 64;
#pragma unroll
    for (int i = 0; i < 4; ++i) {
      int c = i * 256 + tid;
      int row = c >> 3, sl = c & 7;
      int ss = sl ^ (row & 7);
      gload_lds16(A + (bm + row) * K + kb + ss * 8, &As[c * 8]);
      gload_lds16(B + (bn + row) * K + kb + ss * 8, &Bs[c * 8]);
    }
    __syncthreads();
#pragma unroll
    for (int ks = 0; ks < 2; ++ks) {
      s16x8 af[4], bfr[4];
#pragma unroll
      for (int f = 0; f < 4; ++f) {
        int ra = wm * 64 + f * 16 + li;
        int sa = (ks * 4 + g) ^ (ra & 7);
        af[f] = *(const s16x8*)&As[ra * 64 + sa * 8];
        int rb = wn * 64 + f * 16 + li;
        int sb = (ks * 4 + g) ^ (rb & 7);
        bfr[f] = *(const s16x8*)&Bs[rb * 64 + sb * 8];
      }
#pragma unroll
      for (int mi = 0; mi < 4; ++mi)
#pragma unroll
        for (int ni = 0; ni < 4; ++ni)
          acc[mi][ni] = mfma_bf16(af[mi], bfr[ni], acc[mi][ni]);
    }
    __syncthreads();
  }

#pragma unroll
  for (int ni = 0; ni < 4; ++ni) {
    size_t col = bn + wn * 64 + ni * 16 + li;
    float bv = BIAS ? bias[col] : 0.f;
#pragma unroll
    for (int mi = 0; mi < 4; ++mi) {
#pragma unroll
      for (int r = 0; r < 4; ++r) {
        size_t row = bm + wm * 64 + mi * 16 + g * 4 + r;
        if constexpr (OUT_F32) ((float*)Cout)[row * ldc + col] = acc[mi][ni][r] + bv;
        else                   ((u16*)Cout)[row * ldc + col] = f2b(acc[mi][ni][r]);
      }
    }
  }
}

// --- V transpose: qkv v-section [t][h*64+d] -> vT[bh][d][t] ------------------

__global__ __launch_bounds__(256) void transpose_v_kernel(const u16* __restrict__ qkv,
                                                          u16* __restrict__ vT) {
  __shared__ __attribute__((aligned(16))) u16 ts[64][72];
  const int bh = blockIdx.y;
  const int b = bh >> 4, h = bh & 15;
  const int t0 = blockIdx.x * 64;
  const u16* src = qkv + (size_t)(b * 2048 + t0) * 3072 + 2048 + h * 64;
#pragma unroll
  for (int i = 0; i < 2; ++i) {
    int c = i * 256 + threadIdx.x;
    int row = c >> 3, sl = c & 7;
    *(s16x8*)&ts[row][sl * 8] = *(const s16x8*)&src[(size_t)row * 3072 + sl * 8];
  }
  __syncthreads();
  u16* dst = vT + (size_t)bh * 64 * 2048 + t0;
#pragma unroll
  for (int i = 0; i < 2; ++i) {
    int c = i * 256 + threadIdx.x;
    int drow = c >> 3, sl = c & 7;
    s16x8 o;
#pragma unroll
    for (int j = 0; j < 8; ++j) o[j] = (short)ts[sl * 8 + j][drow];
    *(s16x8*)&dst[(size_t)drow * 2048 + sl * 8] = o;
  }
}

// --- flash attention (causal) v2 ---------------------------------------------
// QBLK=64 (4 waves x 16 rows), KVBLK=64. Uniform work via causal pairing:
// block p handles q-tiles (31-p) then (p): always 33 KV iterations.
// Double-buffered K/V LDS with prefetch-before-compute (T3-minimum 2-phase).
// T13 defer-max; swizzled P (pitch 64). LDS = 40960B -> 4 blocks/CU.

__global__ __launch_bounds__(256) void attn_kernel(const u16* __restrict__ qkv,
                                                   const u16* __restrict__ vT,
                                                   u16* __restrict__ out) {
  __shared__ __attribute__((aligned(16))) u16 Ks[2][64 * 64];
  __shared__ __attribute__((aligned(16))) u16 Vs[2][64 * 64];
  __shared__ __attribute__((aligned(16))) u16 Ps[4][16 * 64];

  // XCD grouping: 16 q-pair blocks of one bh land on one XCD (8 bh per XCD)
  const int id  = blockIdx.x;
  const int xcd = id & 7;
  const int rr  = id >> 3;
  const int bh  = xcd * 8 + (rr & 7);
  const int p   = rr >> 3;                 // 0..15

  const int b = bh >> 4, h = bh & 15;
  const int tid = threadIdx.x;
  const int lane = tid & 63;
  const int w = tid >> 6;
  const int g = lane >> 4, li = lane & 15;

  const int tA = 31 - p;
  const int nA = tA + 1;
  const int nTot = nA + p + 1;             // == 33 always

  const u16* kbase = qkv + (size_t)(b * 2048) * 3072 + 1024 + h * 64;
  const u16* vtb   = vT + (size_t)bh * 64 * 2048;
  u16* pl = Ps[w];

  auto stage = [&](int buf, int j0) {
#pragma unroll
    for (int i = 0; i < 2; ++i) {
      int c = i * 256 + tid;
      int row = c >> 3, sl = c & 7, ss = sl ^ (row & 7);
      gload_lds16(kbase + (size_t)(j0 + row) * 3072 + ss * 8, &Ks[buf][c * 8]);
      gload_lds16(vtb + (size_t)row * 2048 + j0 + ss * 8, &Vs[buf][c * 8]);
    }
  };

  stage(0, 0);
  __syncthreads();                         // drain prologue stage

  s16x8 qf[2];
  f32x4 oacc[4];
  float mrow[4], lrow[4];
  int wq0 = 0;
  const float cexp = 0.18033688011112042f; // (1/sqrt(64)) * log2(e)

  for (int s = 0; s < nTot; ++s) {
    const int cur = s & 1;
    const bool inA = s < nA;
    const int t  = inA ? s : s - nA;
    const int qt = inA ? tA : p;
    const int j0 = t * 64;

    // issue next tile's loads BEFORE compute (latency hides under MFMA/softmax)
    if (s + 1 < nTot) {
      int t1 = (s + 1 < nA) ? (s + 1) : (s + 1 - nA);
      stage(cur ^ 1, t1 * 64);
    }

    if (t == 0) {                          // new q-tile: load Q frags, reset state
      const int q0 = qt * 64;
      wq0 = q0 + w * 16;
      const u16* qbase = qkv + (size_t)(b * 2048 + wq0) * 3072 + h * 64;
#pragma unroll
      for (int kk = 0; kk < 2; ++kk)
        qf[kk] = *(const s16x8*)&qbase[(size_t)li * 3072 + kk * 32 + g * 8];
#pragma unroll
      for (int r = 0; r < 4; ++r) { mrow[r] = -1e30f; lrow[r] = 0.f; }
#pragma unroll
      for (int fd = 0; fd < 4; ++fd) oacc[fd] = (f32x4)0.f;
    }

    const u16* ksb = Ks[cur];
    const u16* vsb = Vs[cur];

    // S = Q K^T   (rows: wq0 + g*4+r, cols: j0 + fj*16+li)
    f32x4 sfr[4] = {};
#pragma unroll
    for (int kk = 0; kk < 2; ++kk) {
      s16x8 kf[4];
#pragma unroll
      for (int fj = 0; fj < 4; ++fj) {
        int rk = fj * 16 + li;
        int ssl = (kk * 4 + g) ^ (rk & 7);
        kf[fj] = *(const s16x8*)&ksb[rk * 64 + ssl * 8];
      }
#pragma unroll
      for (int fj = 0; fj < 4; ++fj)
        sfr[fj] = mfma_bf16(qf[kk], kf[fj], sfr[fj]);
    }

    if (t == qt) {                         // diagonal tile: causal mask
#pragma unroll
      for (int fj = 0; fj < 4; ++fj)
#pragma unroll
        for (int r = 0; r < 4; ++r) {
          int ii = wq0 + g * 4 + r;
          int jj = j0 + fj * 16 + li;
          if (jj > ii) sfr[fj][r] = -1e30f;
        }
    }

    // online softmax with T13 defer-max (wave-uniform rescale skip)
    float mx[4];
#pragma unroll
    for (int r = 0; r < 4; ++r) {
      float m0 = fmaxf(fmaxf(sfr[0][r], sfr[1][r]), fmaxf(sfr[2][r], sfr[3][r]));
      m0 = fmaxf(m0, __shfl_xor(m0, 1));
      m0 = fmaxf(m0, __shfl_xor(m0, 2));
      m0 = fmaxf(m0, __shfl_xor(m0, 4));
      m0 = fmaxf(m0, __shfl_xor(m0, 8));
      mx[r] = m0;
    }
    bool need = false;
#pragma unroll
    for (int r = 0; r < 4; ++r) need |= (mx[r] - mrow[r]) * cexp > 8.0f;
    if (__any(need)) {
#pragma unroll
      for (int r = 0; r < 4; ++r) {
        float mnew = fmaxf(mrow[r], mx[r]);
        float sc = exp2f((mrow[r] - mnew) * cexp);
        mrow[r] = mnew;
        lrow[r] *= sc;
#pragma unroll
        for (int fd = 0; fd < 4; ++fd) oacc[fd][r] *= sc;
      }
    }
#pragma unroll
    for (int r = 0; r < 4; ++r) {
      float rs = 0.f;
      const int prow = g * 4 + r;
      const int sw = prow & 7;
#pragma unroll
      for (int fj = 0; fj < 4; ++fj) {
        float pv = exp2f((sfr[fj][r] - mrow[r]) * cexp);
        rs += pv;
        int col = fj * 16 + li;
        pl[prow * 64 + (((col >> 3) ^ sw) * 8) + (col & 7)] = f2b(pv);
      }
      rs += __shfl_xor(rs, 1);
      rs += __shfl_xor(rs, 2);
      rs += __shfl_xor(rs, 4);
      rs += __shfl_xor(rs, 8);
      lrow[r] += rs;
    }

    // O += P V   (A = P[q=li][k contig], B = V^T[d=fd*16+li][k contig])
#pragma unroll
    for (int kk = 0; kk < 2; ++kk) {
      s16x8 pf = *(const s16x8*)&pl[li * 64 + (((kk * 4 + g) ^ (li & 7)) * 8)];
      s16x8 vf[4];
#pragma unroll
      for (int fd = 0; fd < 4; ++fd) {
        int rv = fd * 16 + li;
        int ssl = (kk * 4 + g) ^ (rv & 7);
        vf[fd] = *(const s16x8*)&vsb[rv * 64 + ssl * 8];
      }
#pragma unroll
      for (int fd = 0; fd < 4; ++fd)
        oacc[fd] = mfma_bf16(pf, vf[fd], oacc[fd]);
    }

    if (t == qt) {                         // q-tile done: write output
      u16* ob = out + (size_t)(b * 2048 + wq0) * 1024 + h * 64;
#pragma unroll
      for (int r = 0; r < 4; ++r) {
        float inv = 1.f / lrow[r];
#pragma unroll
        for (int fd = 0; fd < 4; ++fd)
          ob[(size_t)(g * 4 + r) * 1024 + fd * 16 + li] = f2b(oacc[fd][r] * inv);
      }
    }

    __syncthreads();                       // drains prefetch; buf swap safe
  }
}

// --- launch ------------------------------------------------------------------

extern "C" void kernel_launch(void* const* d_in, const int* in_sizes, int n_in,
                              void* d_out, int out_size, void* d_ws, size_t ws_size,
                              hipStream_t stream) {
  const float* x  = (const float*)d_in[0];
  const float* Wq = (const float*)d_in[1];
  const float* Wk = (const float*)d_in[2];
  const float* Wv = (const float*)d_in[3];
  const float* Wp = (const float*)d_in[4];
  const float* bp = (const float*)d_in[5];
  (void)in_sizes; (void)n_in; (void)out_size; (void)ws_size;

  char* ws = (char*)d_ws;
  u16* xb    = (u16*)(ws);                   // [8192][1024]  16 MB
  u16* wqkvb = (u16*)(ws + 16777216);        // [3072][1024]   6 MB
  u16* wpb   = (u16*)(ws + 23068672);        // [1024][1024]   2 MB
  u16* qkv   = (u16*)(ws + 25165824);        // [8192][3072]  48 MB
  u16* vT    = (u16*)(ws + 75497472);        // [64][64][2048] 16 MB
  u16* ao    = (u16*)(ws + 92274688);        // [8192][1024]  16 MB

  cvt_f32_bf16_kernel<<<4096, 256, 0, stream>>>(x, xb);
  cvt_wqkv_kernel<<<12288, 256, 0, stream>>>(Wq, Wk, Wv, wqkvb);
  cvt_f32_bf16_kernel<<<512, 256, 0, stream>>>(Wp, wpb);

  gemm_bt_kernel<false, false><<<dim3(64, 24), 256, 0, stream>>>(
      xb, wqkvb, (void*)qkv, nullptr, 1024, 3072);

  transpose_v_kernel<<<dim3(32, 64), 256, 0, stream>>>(qkv, vT);

  attn_kernel<<<1024, 256, 0, stream>>>(qkv, vT, ao);

  gemm_bt_kernel<true, true><<<dim3(64, 8), 256, 0, stream>>>(
      ao, wpb, d_out, bp, 1024, 1024);
}

// Round 3
// 182.218 us; speedup vs baseline: 1.8497x; 1.2014x over previous
//
#include <hip/hip_runtime.h>
#include <stdint.h>

// ---------------------------------------------------------------------------
// MultiHeadAttention B=4 T=2048 C=1024 H=16 D=64  (fp32 in/out, causal)
// Pipeline: cvt(bf16) -> GEMM(QKV) -> transpose(V) -> flash-attn -> GEMM(proj)+bias
// ---------------------------------------------------------------------------

typedef unsigned short u16;
typedef __attribute__((ext_vector_type(8))) short    s16x8;
typedef __attribute__((ext_vector_type(4))) float    f32x4;
typedef __attribute__((ext_vector_type(2))) uint32_t u32x2;

// --- helpers ---------------------------------------------------------------

__device__ __forceinline__ u16 f2b(float f) {  // f32 -> bf16 RNE
  union { float f; uint32_t u; } v; v.f = f;
  uint32_t r = v.u + 0x7FFFu + ((v.u >> 16) & 1u);
  return (u16)(r >> 16);
}

__device__ __forceinline__ uint32_t cvtpk(float a, float b) {  // [lo=bf16(a), hi=bf16(b)]
  uint32_t r;
  asm("v_cvt_pk_bf16_f32 %0, %1, %2" : "=v"(r) : "v"(a), "v"(b));
  return r;
}

// v_mfma_f32_16x16x32_bf16 via inline asm.
// A frag: lane holds A[m=l&15][k: 8 contig at kk*32+g*8]; B frag: B^T[n=l&15][k contig]
// C/D: row=(l>>4)*4+reg, col=l&15   [verified layout, learn_hip m89/m91]
__device__ __forceinline__ f32x4 mfma_bf16(s16x8 a, s16x8 b, f32x4 c) {
  asm("v_mfma_f32_16x16x32_bf16 %0, %1, %2, %0" : "+v"(c) : "v"(a), "v"(b));
  return c;
}

// async global->LDS, 16B per lane. LDS dest is wave-uniform base + lane*16.
__device__ __forceinline__ void gload_lds16(const void* g, void* l) {
  __builtin_amdgcn_global_load_lds(
      (__attribute__((address_space(1))) void*)(uintptr_t)g,
      (__attribute__((address_space(3))) void*)(uint32_t)(uintptr_t)l,
      16, 0, 0);
}

// --- conversion kernels ------------------------------------------------------

__global__ void cvt_f32_bf16_kernel(const float* __restrict__ in, u16* __restrict__ out) {
  size_t i = (size_t)blockIdx.x * 256 + threadIdx.x;
  const f32x4* p = (const f32x4*)(in + i * 8);
  f32x4 a = p[0], b = p[1];
  s16x8 o;
  o[0]=(short)f2b(a[0]); o[1]=(short)f2b(a[1]); o[2]=(short)f2b(a[2]); o[3]=(short)f2b(a[3]);
  o[4]=(short)f2b(b[0]); o[5]=(short)f2b(b[1]); o[6]=(short)f2b(b[2]); o[7]=(short)f2b(b[3]);
  *(s16x8*)(out + i * 8) = o;
}

// Wq/Wk/Wv [H,C,D] f32 -> wqkvb [3*H*D][C] bf16  (B^T layout for the GEMM)
__global__ void cvt_wqkv_kernel(const float* __restrict__ Wq, const float* __restrict__ Wk,
                                const float* __restrict__ Wv, u16* __restrict__ out) {
  int idx = blockIdx.x * 256 + threadIdx.x;
  int sel = idx >> 20;
  int rem = idx & 1048575;
  int n = rem >> 10, c = rem & 1023;
  int h = n >> 6, d = n & 63;
  const float* W = (sel == 0) ? Wq : ((sel == 1) ? Wk : Wv);
  out[idx] = f2b(W[h * 65536 + c * 64 + d]);
}

// --- GEMM: C[M][N] = A[M][K] * B[N][K]^T  (bf16 in, 128x128 tile, BK=64) ----

template <bool OUT_F32, bool BIAS>
__global__ __launch_bounds__(256) void gemm_bt_kernel(
    const u16* __restrict__ A, const u16* __restrict__ B, void* __restrict__ Cout,
    const float* __restrict__ bias, int K, int ldc)
{
  __shared__ __attribute__((aligned(16))) u16 As[128 * 64];
  __shared__ __attribute__((aligned(16))) u16 Bs[128 * 64];

  const int tid  = threadIdx.x;
  const int lane = tid & 63;
  const int w    = tid >> 6;
  const int wm   = w >> 1, wn = w & 1;
  const int g    = lane >> 4;
  const int li   = lane & 15;
  const size_t bm = (size_t)blockIdx.x * 128;
  const size_t bn = (size_t)blockIdx.y * 128;

  f32x4 acc[4][4] = {};

  const int kIters = K >> 6;
  for (int kt = 0; kt < kIters; ++kt) {
    const int kb = kt * 64;
#pragma unroll
    for (int i = 0; i < 4; ++i) {
      int c = i * 256 + tid;
      int row = c >> 3, sl = c & 7;
      int ss = sl ^ (row & 7);
      gload_lds16(A + (bm + row) * K + kb + ss * 8, &As[c * 8]);
      gload_lds16(B + (bn + row) * K + kb + ss * 8, &Bs[c * 8]);
    }
    __syncthreads();
#pragma unroll
    for (int ks = 0; ks < 2; ++ks) {
      s16x8 af[4], bfr[4];
#pragma unroll
      for (int f = 0; f < 4; ++f) {
        int ra = wm * 64 + f * 16 + li;
        int sa = (ks * 4 + g) ^ (ra & 7);
        af[f] = *(const s16x8*)&As[ra * 64 + sa * 8];
        int rb = wn * 64 + f * 16 + li;
        int sb = (ks * 4 + g) ^ (rb & 7);
        bfr[f] = *(const s16x8*)&Bs[rb * 64 + sb * 8];
      }
#pragma unroll
      for (int mi = 0; mi < 4; ++mi)
#pragma unroll
        for (int ni = 0; ni < 4; ++ni)
          acc[mi][ni] = mfma_bf16(af[mi], bfr[ni], acc[mi][ni]);
    }
    __syncthreads();
  }

#pragma unroll
  for (int ni = 0; ni < 4; ++ni) {
    size_t col = bn + wn * 64 + ni * 16 + li;
    float bv = BIAS ? bias[col] : 0.f;
#pragma unroll
    for (int mi = 0; mi < 4; ++mi) {
#pragma unroll
      for (int r = 0; r < 4; ++r) {
        size_t row = bm + wm * 64 + mi * 16 + g * 4 + r;
        if constexpr (OUT_F32) ((float*)Cout)[row * ldc + col] = acc[mi][ni][r] + bv;
        else                   ((u16*)Cout)[row * ldc + col] = f2b(acc[mi][ni][r]);
      }
    }
  }
}

// --- V transpose: qkv v-section [t][h*64+d] -> vT[bh][d][t] ------------------

__global__ __launch_bounds__(256) void transpose_v_kernel(const u16* __restrict__ qkv,
                                                          u16* __restrict__ vT) {
  __shared__ __attribute__((aligned(16))) u16 ts[64][72];
  const int bh = blockIdx.y;
  const int b = bh >> 4, h = bh & 15;
  const int t0 = blockIdx.x * 64;
  const u16* src = qkv + (size_t)(b * 2048 + t0) * 3072 + 2048 + h * 64;
#pragma unroll
  for (int i = 0; i < 2; ++i) {
    int c = i * 256 + threadIdx.x;
    int row = c >> 3, sl = c & 7;
    *(s16x8*)&ts[row][sl * 8] = *(const s16x8*)&src[(size_t)row * 3072 + sl * 8];
  }
  __syncthreads();
  u16* dst = vT + (size_t)bh * 64 * 2048 + t0;
#pragma unroll
  for (int i = 0; i < 2; ++i) {
    int c = i * 256 + threadIdx.x;
    int drow = c >> 3, sl = c & 7;
    s16x8 o;
#pragma unroll
    for (int j = 0; j < 8; ++j) o[j] = (short)ts[sl * 8 + j][drow];
    *(s16x8*)&dst[(size_t)drow * 2048 + sl * 8] = o;
  }
}

// --- flash attention (causal) v3: swapped QK^T, lane-local softmax -----------
// QBLK=64 (4 waves x 16 q), KVBLK=64. Causal pairing: block p does q-tiles
// (31-p) then (p) -> 33 iterations always. Double-buffered K/V with prefetch.
// S^T = mfma(K, Q): lane owns q = lane&15; 16 in-lane kv values per tile ->
// softmax = in-lane reduce + 2 shfl. P packed via v_cvt_pk_bf16_f32, written
// as 4 ds_write_b64 (slot-XOR swizzle, <=2-way banks), read back as 2 b128.
// O^T = mfma(V^T, P^T). LDS 40960B -> 4 blocks/CU.

__global__ __launch_bounds__(256) void attn_kernel(const u16* __restrict__ qkv,
                                                   const u16* __restrict__ vT,
                                                   u16* __restrict__ out) {
  __shared__ __attribute__((aligned(16))) u16 Ks[2][64 * 64];
  __shared__ __attribute__((aligned(16))) u16 Vs[2][64 * 64];
  __shared__ __attribute__((aligned(16))) u16 Ps[4][16 * 64];

  const int id  = blockIdx.x;
  const int xcd = id & 7;
  const int rr  = id >> 3;
  const int bh  = xcd * 8 + (rr & 7);
  const int p   = rr >> 3;                 // 0..15

  const int b = bh >> 4, h = bh & 15;
  const int tid = threadIdx.x;
  const int lane = tid & 63;
  const int w = tid >> 6;
  const int g = lane >> 4, li = lane & 15;

  const int tA = 31 - p;
  const int nA = tA + 1;
  const int nTot = nA + p + 1;             // == 33 always

  const u16* kbase = qkv + (size_t)(b * 2048) * 3072 + 1024 + h * 64;
  const u16* vtb   = vT + (size_t)bh * 64 * 2048;
  u16* pl = Ps[w];

  auto stage = [&](int buf, int j0) {
#pragma unroll
    for (int i = 0; i < 2; ++i) {
      int c = i * 256 + tid;
      int row = c >> 3, sl = c & 7, ss = sl ^ (row & 7);
      gload_lds16(kbase + (size_t)(j0 + row) * 3072 + ss * 8, &Ks[buf][c * 8]);
      gload_lds16(vtb + (size_t)row * 2048 + j0 + ss * 8, &Vs[buf][c * 8]);
    }
  };

  stage(0, 0);
  __syncthreads();

  s16x8 qf[2];
  f32x4 oacc[4];
  float mrow = -1e30f, lrow = 0.f;
  int wq0 = 0, qglob = 0;
  const float cexp = 0.18033688011112042f; // (1/sqrt(64)) * log2(e)

  for (int s = 0; s < nTot; ++s) {
    const int cur = s & 1;
    const bool inA = s < nA;
    const int t  = inA ? s : s - nA;
    const int qt = inA ? tA : p;
    const int j0 = t * 64;

    // issue next tile's loads BEFORE compute (latency hides under MFMA/softmax)
    if (s + 1 < nTot) {
      int t1 = (s + 1 < nA) ? (s + 1) : (s + 1 - nA);
      stage(cur ^ 1, t1 * 64);
    }

    if (t == 0) {                          // new q-tile: load Q frags, reset state
      wq0 = qt * 64 + w * 16;
      qglob = wq0 + li;
      const u16* qbase = qkv + (size_t)(b * 2048 + qglob) * 3072 + h * 64;
#pragma unroll
      for (int kk = 0; kk < 2; ++kk)
        qf[kk] = *(const s16x8*)&qbase[kk * 32 + g * 8];
      mrow = -1e30f; lrow = 0.f;
#pragma unroll
      for (int fd = 0; fd < 4; ++fd) oacc[fd] = (f32x4)0.f;
    }

    const u16* ksb = Ks[cur];
    const u16* vsb = Vs[cur];

    // S^T = K Q^T   (lane: q = li fixed; kv = fj*16 + g*4 + r)
    f32x4 sfr[4] = {};
#pragma unroll
    for (int kk = 0; kk < 2; ++kk) {
      s16x8 kf[4];
#pragma unroll
      for (int fj = 0; fj < 4; ++fj) {
        int rk = fj * 16 + li;
        int ssl = (kk * 4 + g) ^ (rk & 7);
        kf[fj] = *(const s16x8*)&ksb[rk * 64 + ssl * 8];
      }
#pragma unroll
      for (int fj = 0; fj < 4; ++fj)
        sfr[fj] = mfma_bf16(kf[fj], qf[kk], sfr[fj]);
    }

    if (t == qt) {                         // diagonal tile: causal mask
#pragma unroll
      for (int fj = 0; fj < 4; ++fj)
#pragma unroll
        for (int r = 0; r < 4; ++r) {
          int jj = j0 + fj * 16 + g * 4 + r;
          if (jj > qglob) sfr[fj][r] = -1e30f;
        }
    }

    // tile max for this lane's q: 16 in-lane values + 2 shfl
    float mx = sfr[0][0];
#pragma unroll
    for (int fj = 0; fj < 4; ++fj)
#pragma unroll
      for (int r = 0; r < 4; ++r) mx = fmaxf(mx, sfr[fj][r]);
    mx = fmaxf(mx, __shfl_xor(mx, 16));
    mx = fmaxf(mx, __shfl_xor(mx, 32));

    // T13 defer-max: rescale only when the running max moved materially
    bool need = (mx - mrow) * cexp > 8.0f;
    if (__any(need)) {
      float mnew = fmaxf(mrow, mx);
      float sc = exp2f((mrow - mnew) * cexp);
      mrow = mnew;
      lrow *= sc;
#pragma unroll
      for (int fd = 0; fd < 4; ++fd)
#pragma unroll
        for (int r = 0; r < 4; ++r) oacc[fd][r] *= sc;
    }

    // exp, row-sum, pack to bf16, store P[q=li][kv] (slot-XOR swizzled)
    float rs = 0.f;
    const int lsw = li & 14;
#pragma unroll
    for (int fj = 0; fj < 4; ++fj) {
      float p0 = exp2f((sfr[fj][0] - mrow) * cexp);
      float p1 = exp2f((sfr[fj][1] - mrow) * cexp);
      float p2 = exp2f((sfr[fj][2] - mrow) * cexp);
      float p3 = exp2f((sfr[fj][3] - mrow) * cexp);
      rs += (p0 + p1) + (p2 + p3);
      u32x2 wv = { cvtpk(p0, p1), cvtpk(p2, p3) };
      int phys = (4 * fj + g) ^ lsw;       // 8B slots, bijective per row
      *(u32x2*)&pl[li * 64 + phys * 4] = wv;
    }
    rs += __shfl_xor(rs, 16);
    rs += __shfl_xor(rs, 32);
    lrow += rs;

    // O^T += V^T P^T  (A = V^T[d][kv contig], B = P[q=li][kv contig])
#pragma unroll
    for (int kk = 0; kk < 2; ++kk) {
      int sr = (8 * kk + 2 * g) ^ lsw;     // even -> 16B aligned, ordered pair
      s16x8 pf = *(const s16x8*)&pl[li * 64 + sr * 4];
      s16x8 vf[4];
#pragma unroll
      for (int fd = 0; fd < 4; ++fd) {
        int rv = fd * 16 + li;
        int ssl = (kk * 4 + g) ^ (rv & 7);
        vf[fd] = *(const s16x8*)&vsb[rv * 64 + ssl * 8];
      }
#pragma unroll
      for (int fd = 0; fd < 4; ++fd)
        oacc[fd] = mfma_bf16(vf[fd], pf, oacc[fd]);
    }

    if (t == qt) {                         // q-tile done: write output (b64 packed)
      float inv = 1.f / lrow;
      u16* ob = out + (size_t)(b * 2048 + qglob) * 1024 + h * 64;
#pragma unroll
      for (int fd = 0; fd < 4; ++fd) {
        u32x2 wv = { cvtpk(oacc[fd][0] * inv, oacc[fd][1] * inv),
                     cvtpk(oacc[fd][2] * inv, oacc[fd][3] * inv) };
        *(u32x2*)&ob[fd * 16 + g * 4] = wv;
      }
    }

    __syncthreads();                       // drains prefetch; buf swap safe
  }
}

// --- launch ------------------------------------------------------------------

extern "C" void kernel_launch(void* const* d_in, const int* in_sizes, int n_in,
                              void* d_out, int out_size, void* d_ws, size_t ws_size,
                              hipStream_t stream) {
  const float* x  = (const float*)d_in[0];
  const float* Wq = (const float*)d_in[1];
  const float* Wk = (const float*)d_in[2];
  const float* Wv = (const float*)d_in[3];
  const float* Wp = (const float*)d_in[4];
  const float* bp = (const float*)d_in[5];
  (void)in_sizes; (void)n_in; (void)out_size; (void)ws_size;

  char* ws = (char*)d_ws;
  u16* xb    = (u16*)(ws);                   // [8192][1024]  16 MB
  u16* wqkvb = (u16*)(ws + 16777216);        // [3072][1024]   6 MB
  u16* wpb   = (u16*)(ws + 23068672);        // [1024][1024]   2 MB
  u16* qkv   = (u16*)(ws + 25165824);        // [8192][3072]  48 MB
  u16* vT    = (u16*)(ws + 75497472);        // [64][64][2048] 16 MB
  u16* ao    = (u16*)(ws + 92274688);        // [8192][1024]  16 MB

  cvt_f32_bf16_kernel<<<4096, 256, 0, stream>>>(x, xb);
  cvt_wqkv_kernel<<<12288, 256, 0, stream>>>(Wq, Wk, Wv, wqkvb);
  cvt_f32_bf16_kernel<<<512, 256, 0, stream>>>(Wp, wpb);

  gemm_bt_kernel<false, false><<<dim3(64, 24), 256, 0, stream>>>(
      xb, wqkvb, (void*)qkv, nullptr, 1024, 3072);

  transpose_v_kernel<<<dim3(32, 64), 256, 0, stream>>>(qkv, vT);

  attn_kernel<<<1024, 256, 0, stream>>>(qkv, vT, ao);

  gemm_bt_kernel<true, true><<<dim3(64, 8), 256, 0, stream>>>(
      ao, wpb, d_out, bp, 1024, 1024);
}

// Round 4
// 175.667 us; speedup vs baseline: 1.9187x; 1.0373x over previous
//
#include <hip/hip_runtime.h>
#include <stdint.h>

// ---------------------------------------------------------------------------
// MultiHeadAttention B=4 T=2048 C=1024 H=16 D=64  (fp32 in/out, causal)
// Pipeline: cvt(bf16) -> GEMM(QKV, v written transposed) -> flash-attn -> GEMM(proj)+bias
// ---------------------------------------------------------------------------

typedef unsigned short u16;
typedef __attribute__((ext_vector_type(8))) short    s16x8;
typedef __attribute__((ext_vector_type(4))) float    f32x4;
typedef __attribute__((ext_vector_type(2))) uint32_t u32x2;

// --- helpers ---------------------------------------------------------------

__device__ __forceinline__ u16 f2b(float f) {  // f32 -> bf16 RNE
  union { float f; uint32_t u; } v; v.f = f;
  uint32_t r = v.u + 0x7FFFu + ((v.u >> 16) & 1u);
  return (u16)(r >> 16);
}

__device__ __forceinline__ uint32_t cvtpk(float a, float b) {  // [lo=bf16(a), hi=bf16(b)]
  uint32_t r;
  asm("v_cvt_pk_bf16_f32 %0, %1, %2" : "=v"(r) : "v"(a), "v"(b));
  return r;
}

// v_mfma_f32_16x16x32_bf16. A: lane holds A[m=l&15][8k contig]; B: B^T[n=l&15][8k contig]
// C/D: row=(l>>4)*4+reg, col=l&15
__device__ __forceinline__ f32x4 mfma_bf16(s16x8 a, s16x8 b, f32x4 c) {
  asm("v_mfma_f32_16x16x32_bf16 %0, %1, %2, %0" : "+v"(c) : "v"(a), "v"(b));
  return c;
}

// async global->LDS, 16B per lane. LDS dest is wave-uniform base + lane*16.
__device__ __forceinline__ void gload_lds16(const void* g, void* l) {
  __builtin_amdgcn_global_load_lds(
      (__attribute__((address_space(1))) void*)(uintptr_t)g,
      (__attribute__((address_space(3))) void*)(uint32_t)(uintptr_t)l,
      16, 0, 0);
}

// --- conversion kernels ------------------------------------------------------

__global__ void cvt_f32_bf16_kernel(const float* __restrict__ in, u16* __restrict__ out) {
  size_t i = (size_t)blockIdx.x * 256 + threadIdx.x;
  const f32x4* p = (const f32x4*)(in + i * 8);
  f32x4 a = p[0], b = p[1];
  s16x8 o;
  o[0]=(short)f2b(a[0]); o[1]=(short)f2b(a[1]); o[2]=(short)f2b(a[2]); o[3]=(short)f2b(a[3]);
  o[4]=(short)f2b(b[0]); o[5]=(short)f2b(b[1]); o[6]=(short)f2b(b[2]); o[7]=(short)f2b(b[3]);
  *(s16x8*)(out + i * 8) = o;
}

// Wq/Wk/Wv [H,C,D] f32 -> wqkvb [3*H*D][C] bf16  (B^T layout for the GEMM)
__global__ void cvt_wqkv_kernel(const float* __restrict__ Wq, const float* __restrict__ Wk,
                                const float* __restrict__ Wv, u16* __restrict__ out) {
  int idx = blockIdx.x * 256 + threadIdx.x;
  int sel = idx >> 20;
  int rem = idx & 1048575;
  int n = rem >> 10, c = rem & 1023;
  int h = n >> 6, d = n & 63;
  const float* W = (sel == 0) ? Wq : ((sel == 1) ? Wk : Wv);
  out[idx] = f2b(W[h * 65536 + c * 64 + d]);
}

// --- GEMM: C[M][N] = A[M][K] * B[N][K]^T  (bf16 in, 128x128 tile, BK=64) ----
// MODE 1: f32 out + bias.  MODE 2: qkv: cols<2048 -> bf16 C; v cols -> vT transposed.

template <int MODE>
__global__ __launch_bounds__(256) void gemm_bt_kernel(
    const u16* __restrict__ A, const u16* __restrict__ B, void* __restrict__ Cout,
    const float* __restrict__ bias, u16* __restrict__ vTout, int K, int ldc)
{
  __shared__ __attribute__((aligned(16))) u16 As[128 * 64];
  __shared__ __attribute__((aligned(16))) u16 Bs[128 * 64];

  const int tid  = threadIdx.x;
  const int lane = tid & 63;
  const int w    = tid >> 6;
  const int wm   = w >> 1, wn = w & 1;
  const int g    = lane >> 4;
  const int li   = lane & 15;
  const size_t bm = (size_t)blockIdx.x * 128;
  const size_t bn = (size_t)blockIdx.y * 128;

  f32x4 acc[4][4] = {};

  const int kIters = K >> 6;
  for (int kt = 0; kt < kIters; ++kt) {
    const int kb = kt * 64;
#pragma unroll
    for (int i = 0; i < 4; ++i) {
      int c = i * 256 + tid;
      int row = c >> 3, sl = c & 7;
      int ss = sl ^ (row & 7);
      gload_lds16(A + (bm + row) * K + kb + ss * 8, &As[c * 8]);
      gload_lds16(B + (bn + row) * K + kb + ss * 8, &Bs[c * 8]);
    }
    __syncthreads();
#pragma unroll
    for (int ks = 0; ks < 2; ++ks) {
      s16x8 af[4], bfr[4];
#pragma unroll
      for (int f = 0; f < 4; ++f) {
        int ra = wm * 64 + f * 16 + li;
        int sa = (ks * 4 + g) ^ (ra & 7);
        af[f] = *(const s16x8*)&As[ra * 64 + sa * 8];
        int rb = wn * 64 + f * 16 + li;
        int sb = (ks * 4 + g) ^ (rb & 7);
        bfr[f] = *(const s16x8*)&Bs[rb * 64 + sb * 8];
      }
#pragma unroll
      for (int mi = 0; mi < 4; ++mi)
#pragma unroll
        for (int ni = 0; ni < 4; ++ni)
          acc[mi][ni] = mfma_bf16(af[mi], bfr[ni], acc[mi][ni]);
    }
    __syncthreads();
  }

  if constexpr (MODE == 1) {
#pragma unroll
    for (int ni = 0; ni < 4; ++ni) {
      size_t col = bn + wn * 64 + ni * 16 + li;
      float bv = bias[col];
#pragma unroll
      for (int mi = 0; mi < 4; ++mi)
#pragma unroll
        for (int r = 0; r < 4; ++r) {
          size_t row = bm + wm * 64 + mi * 16 + g * 4 + r;
          ((float*)Cout)[row * ldc + col] = acc[mi][ni][r] + bv;
        }
    }
  } else {
    if (bn < 2048) {                 // q|k region: bf16 into qkv
#pragma unroll
      for (int ni = 0; ni < 4; ++ni) {
        size_t col = bn + wn * 64 + ni * 16 + li;
#pragma unroll
        for (int mi = 0; mi < 4; ++mi)
#pragma unroll
          for (int r = 0; r < 4; ++r) {
            size_t row = bm + wm * 64 + mi * 16 + g * 4 + r;
            ((u16*)Cout)[row * ldc + col] = f2b(acc[mi][ni][r]);
          }
      }
    } else {                         // v region: write transposed into vT[bh][d][t]
      const int hb = (int)((bn - 2048) >> 6) + wn;
      const int bb = (int)(bm >> 11);
      const int t0b = ((int)bm & 2047) + wm * 64 + g * 4;
      u16* vrow = vTout + (size_t)((bb * 16 + hb) * 64) * 2048;
#pragma unroll
      for (int ni = 0; ni < 4; ++ni) {
        u16* vd_ = vrow + (size_t)(ni * 16 + li) * 2048;
#pragma unroll
        for (int mi = 0; mi < 4; ++mi) {
          u32x2 wv = { cvtpk(acc[mi][ni][0], acc[mi][ni][1]),
                       cvtpk(acc[mi][ni][2], acc[mi][ni][3]) };
          *(u32x2*)&vd_[t0b + mi * 16] = wv;
        }
      }
    }
  }
}

// --- flash attention (causal) v4: swapped QK^T + hoisted offsets -------------
// QBLK=64 (4 waves x 16 q), KVBLK=64, causal pairing (33 iters/block).
// Double-buffered K/V, prefetch-before-compute. Lane-local softmax (q=li),
// P via cvt_pk + b64 swizzled LDS. __launch_bounds__(256,4): LDS caps at
// 4 blocks/CU = 4 waves/SIMD, so give the allocator 128 VGPRs to hoist.

__global__ __launch_bounds__(256, 4) void attn_kernel(const u16* __restrict__ qkv,
                                                      const u16* __restrict__ vT,
                                                      u16* __restrict__ out) {
  __shared__ __attribute__((aligned(16))) u16 Ks[2][64 * 64];
  __shared__ __attribute__((aligned(16))) u16 Vs[2][64 * 64];
  __shared__ __attribute__((aligned(16))) u16 Ps[4][16 * 64];

  const int id  = blockIdx.x;
  const int xcd = id & 7;
  const int rr  = id >> 3;
  const int bh  = xcd * 8 + (rr & 7);
  const int p   = rr >> 3;                 // 0..15

  const int b = bh >> 4, h = bh & 15;
  const int tid = threadIdx.x;
  const int lane = tid & 63;
  const int w = tid >> 6;
  const int g = lane >> 4, li = lane & 15;

  const int tA = 31 - p;
  const int nA = tA + 1;
  const int nTot = nA + p + 1;             // == 33 always

  const u16* kbase = qkv + (size_t)(b * 2048) * 3072 + 1024 + h * 64;
  const u16* vtb   = vT + (size_t)bh * 64 * 2048;
  u16* pl = Ps[w];

  // ---- hoisted per-lane offsets (all loop-invariant) ----
  const int srow = tid >> 3;
  const int ssl0 = (tid & 7) ^ (srow & 7);
  const int kge0 = srow * 3072 + ssl0 * 8;       // + j0*3072 per iter
  const int vge0 = srow * 2048 + ssl0 * 8;       // + j0 per iter
  u16* const kd0 = &Ks[0][tid * 8];              // + buf*4096
  u16* const vd0 = &Vs[0][tid * 8];

  int foff[2][4];                                 // kf/vf fragment offsets
#pragma unroll
  for (int kk = 0; kk < 2; ++kk)
#pragma unroll
    for (int fj = 0; fj < 4; ++fj) {
      int rk = fj * 16 + li;
      foff[kk][fj] = rk * 64 + (((kk * 4 + g) ^ (rk & 7)) * 8);
    }
  const int lsw = li & 14;
  int pwoff[4], proff[2];
#pragma unroll
  for (int fj = 0; fj < 4; ++fj) pwoff[fj] = li * 64 + (((4 * fj + g) ^ lsw) * 4);
#pragma unroll
  for (int kk = 0; kk < 2; ++kk) proff[kk] = li * 64 + (((8 * kk + 2 * g) ^ lsw) * 4);

  auto stage = [&](int buf, int j0) {
    const u16* kp = kbase + (size_t)j0 * 3072;
    const u16* vp = vtb + j0;
    u16* kd = kd0 + buf * 4096;
    u16* vd = vd0 + buf * 4096;
    gload_lds16(kp + kge0, kd);
    gload_lds16(kp + kge0 + 32 * 3072, kd + 2048);
    gload_lds16(vp + vge0, vd);
    gload_lds16(vp + vge0 + 32 * 2048, vd + 2048);
  };

  stage(0, 0);
  __syncthreads();

  s16x8 qf[2];
  f32x4 oacc[4];
  float mrow = -1e30f, lrow = 0.f;
  int qglob = 0;
  const float cexp = 0.18033688011112042f; // (1/sqrt(64)) * log2(e)

  for (int s = 0; s < nTot; ++s) {
    const int cur = s & 1;
    const bool inA = s < nA;
    const int t  = inA ? s : s - nA;
    const int qt = inA ? tA : p;
    const int j0 = t * 64;

    if (s + 1 < nTot) {                    // prefetch next tile before compute
      int t1 = (s + 1 < nA) ? (s + 1) : (s + 1 - nA);
      stage(cur ^ 1, t1 * 64);
    }

    if (t == 0) {                          // new q-tile: load Q frags, reset state
      qglob = qt * 64 + w * 16 + li;
      const u16* qbase = qkv + (size_t)(b * 2048 + qglob) * 3072 + h * 64;
#pragma unroll
      for (int kk = 0; kk < 2; ++kk)
        qf[kk] = *(const s16x8*)&qbase[kk * 32 + g * 8];
      mrow = -1e30f; lrow = 0.f;
#pragma unroll
      for (int fd = 0; fd < 4; ++fd) oacc[fd] = (f32x4)0.f;
    }

    const u16* ksb = &Ks[0][0] + cur * 4096;
    const u16* vsb = &Vs[0][0] + cur * 4096;

    // S^T = K Q^T   (lane: q = li fixed; kv = fj*16 + g*4 + r)
    f32x4 sfr[4] = {};
    __builtin_amdgcn_s_setprio(1);
#pragma unroll
    for (int kk = 0; kk < 2; ++kk) {
      s16x8 kf[4];
#pragma unroll
      for (int fj = 0; fj < 4; ++fj) kf[fj] = *(const s16x8*)&ksb[foff[kk][fj]];
#pragma unroll
      for (int fj = 0; fj < 4; ++fj) sfr[fj] = mfma_bf16(kf[fj], qf[kk], sfr[fj]);
    }
    __builtin_amdgcn_s_setprio(0);

    if (t == qt) {                         // diagonal tile: causal mask
#pragma unroll
      for (int fj = 0; fj < 4; ++fj)
#pragma unroll
        for (int r = 0; r < 4; ++r) {
          int jj = j0 + fj * 16 + g * 4 + r;
          if (jj > qglob) sfr[fj][r] = -1e30f;
        }
    }

    // tile max for this lane's q: 16 in-lane values + 2 shfl
    float mx = sfr[0][0];
#pragma unroll
    for (int fj = 0; fj < 4; ++fj)
#pragma unroll
      for (int r = 0; r < 4; ++r) mx = fmaxf(mx, sfr[fj][r]);
    mx = fmaxf(mx, __shfl_xor(mx, 16));
    mx = fmaxf(mx, __shfl_xor(mx, 32));

    // T13 defer-max
    bool need = (mx - mrow) * cexp > 8.0f;
    if (__any(need)) {
      float mnew = fmaxf(mrow, mx);
      float sc = exp2f((mrow - mnew) * cexp);
      mrow = mnew;
      lrow *= sc;
#pragma unroll
      for (int fd = 0; fd < 4; ++fd)
#pragma unroll
        for (int r = 0; r < 4; ++r) oacc[fd][r] *= sc;
    }

    // exp, row-sum, pack to bf16, store P (slot-XOR swizzled b64)
    float rs = 0.f;
#pragma unroll
    for (int fj = 0; fj < 4; ++fj) {
      float p0 = exp2f((sfr[fj][0] - mrow) * cexp);
      float p1 = exp2f((sfr[fj][1] - mrow) * cexp);
      float p2 = exp2f((sfr[fj][2] - mrow) * cexp);
      float p3 = exp2f((sfr[fj][3] - mrow) * cexp);
      rs += (p0 + p1) + (p2 + p3);
      u32x2 wv = { cvtpk(p0, p1), cvtpk(p2, p3) };
      *(u32x2*)&pl[pwoff[fj]] = wv;
    }
    rs += __shfl_xor(rs, 16);
    rs += __shfl_xor(rs, 32);
    lrow += rs;

    // O^T += V^T P^T
    __builtin_amdgcn_s_setprio(1);
#pragma unroll
    for (int kk = 0; kk < 2; ++kk) {
      s16x8 pf = *(const s16x8*)&pl[proff[kk]];
      s16x8 vf[4];
#pragma unroll
      for (int fd = 0; fd < 4; ++fd) vf[fd] = *(const s16x8*)&vsb[foff[kk][fd]];
#pragma unroll
      for (int fd = 0; fd < 4; ++fd) oacc[fd] = mfma_bf16(vf[fd], pf, oacc[fd]);
    }
    __builtin_amdgcn_s_setprio(0);

    if (t == qt) {                         // q-tile done: write output (b64 packed)
      float inv = 1.f / lrow;
      u16* ob = out + (size_t)(b * 2048 + qglob) * 1024 + h * 64;
#pragma unroll
      for (int fd = 0; fd < 4; ++fd) {
        u32x2 wv = { cvtpk(oacc[fd][0] * inv, oacc[fd][1] * inv),
                     cvtpk(oacc[fd][2] * inv, oacc[fd][3] * inv) };
        *(u32x2*)&ob[fd * 16 + g * 4] = wv;
      }
    }

    __syncthreads();                       // drains prefetch; buf swap safe
  }
}

// --- launch ------------------------------------------------------------------

extern "C" void kernel_launch(void* const* d_in, const int* in_sizes, int n_in,
                              void* d_out, int out_size, void* d_ws, size_t ws_size,
                              hipStream_t stream) {
  const float* x  = (const float*)d_in[0];
  const float* Wq = (const float*)d_in[1];
  const float* Wk = (const float*)d_in[2];
  const float* Wv = (const float*)d_in[3];
  const float* Wp = (const float*)d_in[4];
  const float* bp = (const float*)d_in[5];
  (void)in_sizes; (void)n_in; (void)out_size; (void)ws_size;

  char* ws = (char*)d_ws;
  u16* xb    = (u16*)(ws);                   // [8192][1024]  16 MB
  u16* wqkvb = (u16*)(ws + 16777216);        // [3072][1024]   6 MB
  u16* wpb   = (u16*)(ws + 23068672);        // [1024][1024]   2 MB
  u16* qkv   = (u16*)(ws + 25165824);        // [8192][3072]  48 MB (v third unused)
  u16* vT    = (u16*)(ws + 75497472);        // [64][64][2048] 16 MB
  u16* ao    = (u16*)(ws + 92274688);        // [8192][1024]  16 MB

  cvt_f32_bf16_kernel<<<4096, 256, 0, stream>>>(x, xb);
  cvt_wqkv_kernel<<<12288, 256, 0, stream>>>(Wq, Wk, Wv, wqkvb);
  cvt_f32_bf16_kernel<<<512, 256, 0, stream>>>(Wp, wpb);

  gemm_bt_kernel<2><<<dim3(64, 24), 256, 0, stream>>>(
      xb, wqkvb, (void*)qkv, nullptr, vT, 1024, 3072);

  attn_kernel<<<1024, 256, 0, stream>>>(qkv, vT, ao);

  gemm_bt_kernel<1><<<dim3(64, 8), 256, 0, stream>>>(
      ao, wpb, d_out, bp, nullptr, 1024, 1024);
}

// Round 5
// 174.650 us; speedup vs baseline: 1.9298x; 1.0058x over previous
//
#include <hip/hip_runtime.h>
#include <stdint.h>

// ---------------------------------------------------------------------------
// MultiHeadAttention B=4 T=2048 C=1024 H=16 D=64  (fp32 in/out, causal)
// Pipeline: cvt(bf16) -> GEMM(QKV, v written transposed) -> flash-attn -> GEMM(proj)+bias
// ---------------------------------------------------------------------------

typedef unsigned short u16;
typedef __attribute__((ext_vector_type(8))) short    s16x8;
typedef __attribute__((ext_vector_type(4))) float    f32x4;
typedef __attribute__((ext_vector_type(2))) uint32_t u32x2;

// --- helpers ---------------------------------------------------------------

__device__ __forceinline__ u16 f2b(float f) {  // f32 -> bf16 RNE
  union { float f; uint32_t u; } v; v.f = f;
  uint32_t r = v.u + 0x7FFFu + ((v.u >> 16) & 1u);
  return (u16)(r >> 16);
}

__device__ __forceinline__ uint32_t cvtpk(float a, float b) {  // [lo=bf16(a), hi=bf16(b)]
  uint32_t r;
  asm("v_cvt_pk_bf16_f32 %0, %1, %2" : "=v"(r) : "v"(a), "v"(b));
  return r;
}

// v_mfma_f32_16x16x32_bf16. A: lane holds A[m=l&15][8k contig]; B: B^T[n=l&15][8k contig]
// C/D: row=(l>>4)*4+reg, col=l&15
__device__ __forceinline__ f32x4 mfma_bf16(s16x8 a, s16x8 b, f32x4 c) {
  asm("v_mfma_f32_16x16x32_bf16 %0, %1, %2, %0" : "+v"(c) : "v"(a), "v"(b));
  return c;
}

// async global->LDS, 16B per lane. LDS dest is wave-uniform base + lane*16.
__device__ __forceinline__ void gload_lds16(const void* g, void* l) {
  __builtin_amdgcn_global_load_lds(
      (__attribute__((address_space(1))) void*)(uintptr_t)g,
      (__attribute__((address_space(3))) void*)(uint32_t)(uintptr_t)l,
      16, 0, 0);
}

// --- conversion kernels ------------------------------------------------------

__global__ void cvt_f32_bf16_kernel(const float* __restrict__ in, u16* __restrict__ out) {
  size_t i = (size_t)blockIdx.x * 256 + threadIdx.x;
  const f32x4* p = (const f32x4*)(in + i * 8);
  f32x4 a = p[0], b = p[1];
  s16x8 o;
  o[0]=(short)f2b(a[0]); o[1]=(short)f2b(a[1]); o[2]=(short)f2b(a[2]); o[3]=(short)f2b(a[3]);
  o[4]=(short)f2b(b[0]); o[5]=(short)f2b(b[1]); o[6]=(short)f2b(b[2]); o[7]=(short)f2b(b[3]);
  *(s16x8*)(out + i * 8) = o;
}

// Wq/Wk/Wv [H,C,D] f32 -> wqkvb [3*H*D][C] bf16  (B^T layout for the GEMM)
__global__ void cvt_wqkv_kernel(const float* __restrict__ Wq, const float* __restrict__ Wk,
                                const float* __restrict__ Wv, u16* __restrict__ out) {
  int idx = blockIdx.x * 256 + threadIdx.x;
  int sel = idx >> 20;
  int rem = idx & 1048575;
  int n = rem >> 10, c = rem & 1023;
  int h = n >> 6, d = n & 63;
  const float* W = (sel == 0) ? Wq : ((sel == 1) ? Wk : Wv);
  out[idx] = f2b(W[h * 65536 + c * 64 + d]);
}

// --- GEMM: C[M][N] = A[M][K] * B[N][K]^T  (bf16 in, 128x128 tile, BK=64) ----
// MODE 1: f32 out + bias.  MODE 2: qkv: cols<2048 -> bf16 C; v cols -> vT transposed.

template <int MODE>
__global__ __launch_bounds__(256) void gemm_bt_kernel(
    const u16* __restrict__ A, const u16* __restrict__ B, void* __restrict__ Cout,
    const float* __restrict__ bias, u16* __restrict__ vTout, int K, int ldc)
{
  __shared__ __attribute__((aligned(16))) u16 As[128 * 64];
  __shared__ __attribute__((aligned(16))) u16 Bs[128 * 64];

  const int tid  = threadIdx.x;
  const int lane = tid & 63;
  const int w    = tid >> 6;
  const int wm   = w >> 1, wn = w & 1;
  const int g    = lane >> 4;
  const int li   = lane & 15;
  const size_t bm = (size_t)blockIdx.x * 128;
  const size_t bn = (size_t)blockIdx.y * 128;

  f32x4 acc[4][4] = {};

  const int kIters = K >> 6;
  for (int kt = 0; kt < kIters; ++kt) {
    const int kb = kt * 64;
#pragma unroll
    for (int i = 0; i < 4; ++i) {
      int c = i * 256 + tid;
      int row = c >> 3, sl = c & 7;
      int ss = sl ^ (row & 7);
      gload_lds16(A + (bm + row) * K + kb + ss * 8, &As[c * 8]);
      gload_lds16(B + (bn + row) * K + kb + ss * 8, &Bs[c * 8]);
    }
    __syncthreads();
#pragma unroll
    for (int ks = 0; ks < 2; ++ks) {
      s16x8 af[4], bfr[4];
#pragma unroll
      for (int f = 0; f < 4; ++f) {
        int ra = wm * 64 + f * 16 + li;
        int sa = (ks * 4 + g) ^ (ra & 7);
        af[f] = *(const s16x8*)&As[ra * 64 + sa * 8];
        int rb = wn * 64 + f * 16 + li;
        int sb = (ks * 4 + g) ^ (rb & 7);
        bfr[f] = *(const s16x8*)&Bs[rb * 64 + sb * 8];
      }
#pragma unroll
      for (int mi = 0; mi < 4; ++mi)
#pragma unroll
        for (int ni = 0; ni < 4; ++ni)
          acc[mi][ni] = mfma_bf16(af[mi], bfr[ni], acc[mi][ni]);
    }
    __syncthreads();
  }

  if constexpr (MODE == 1) {
#pragma unroll
    for (int ni = 0; ni < 4; ++ni) {
      size_t col = bn + wn * 64 + ni * 16 + li;
      float bv = bias[col];
#pragma unroll
      for (int mi = 0; mi < 4; ++mi)
#pragma unroll
        for (int r = 0; r < 4; ++r) {
          size_t row = bm + wm * 64 + mi * 16 + g * 4 + r;
          ((float*)Cout)[row * ldc + col] = acc[mi][ni][r] + bv;
        }
    }
  } else {
    if (bn < 2048) {                 // q|k region: bf16 into qkv
#pragma unroll
      for (int ni = 0; ni < 4; ++ni) {
        size_t col = bn + wn * 64 + ni * 16 + li;
#pragma unroll
        for (int mi = 0; mi < 4; ++mi)
#pragma unroll
          for (int r = 0; r < 4; ++r) {
            size_t row = bm + wm * 64 + mi * 16 + g * 4 + r;
            ((u16*)Cout)[row * ldc + col] = f2b(acc[mi][ni][r]);
          }
      }
    } else {                         // v region: write transposed into vT[bh][d][t]
      const int hb = (int)((bn - 2048) >> 6) + wn;
      const int bb = (int)(bm >> 11);
      const int t0b = ((int)bm & 2047) + wm * 64 + g * 4;
      u16* vrow = vTout + (size_t)((bb * 16 + hb) * 64) * 2048;
#pragma unroll
      for (int ni = 0; ni < 4; ++ni) {
        u16* vd_ = vrow + (size_t)(ni * 16 + li) * 2048;
#pragma unroll
        for (int mi = 0; mi < 4; ++mi) {
          u32x2 wv = { cvtpk(acc[mi][ni][0], acc[mi][ni][1]),
                       cvtpk(acc[mi][ni][2], acc[mi][ni][3]) };
          *(u32x2*)&vd_[t0b + mi * 16] = wv;
        }
      }
    }
  }
}

// --- flash attention (causal) v5 ---------------------------------------------
// QBLK=128 (4 waves x 32 q via 2 fragments), KVBLK=64. Causal pairing:
// block p in 0..7 does q-tiles (15-p) then (p): 34 kv-iters always.
// Critical-path shfl elimination:
//  - lrow kept as PER-LANE partial; cross-lane sum once per q-tile.
//  - max-reduce only when __any(lane-local max > mrow + THR) (T13 extended);
//    common path has ZERO cross-lane ops.
// Double-buffered K/V, prefetch-before-compute. LDS 48KB -> grid 512 = 2/CU.

__global__ __launch_bounds__(256, 2) void attn_kernel(const u16* __restrict__ qkv,
                                                      const u16* __restrict__ vT,
                                                      u16* __restrict__ out) {
  __shared__ __attribute__((aligned(16))) u16 Ks[2][64 * 64];
  __shared__ __attribute__((aligned(16))) u16 Vs[2][64 * 64];
  __shared__ __attribute__((aligned(16))) u16 Ps[4][32 * 64];

  const int id  = blockIdx.x;                // 512 blocks
  const int xcd = id & 7;
  const int rr  = id >> 3;
  const int bh  = xcd * 8 + (rr & 7);        // 8 bh per XCD
  const int p   = rr >> 3;                   // 0..7

  const int b = bh >> 4, h = bh & 15;
  const int tid = threadIdx.x;
  const int lane = tid & 63;
  const int w = tid >> 6;
  const int g = lane >> 4, li = lane & 15;

  const int tA  = 15 - p;
  const int nAi = 2 * (tA + 1);              // iters in phase A
  const int nTot = 34;

  const u16* kbase = qkv + (size_t)(b * 2048) * 3072 + 1024 + h * 64;
  const u16* vtb   = vT + (size_t)bh * 64 * 2048;
  u16* pl = Ps[w];

  // hoisted per-lane offsets
  const int srow = tid >> 3;
  const int ssl0 = (tid & 7) ^ (srow & 7);
  const int kge0 = srow * 3072 + ssl0 * 8;
  const int vge0 = srow * 2048 + ssl0 * 8;
  u16* const kd0 = &Ks[0][tid * 8];
  u16* const vd0 = &Vs[0][tid * 8];

  int foff[2][4];                            // kf/vf fragment offsets
#pragma unroll
  for (int kk = 0; kk < 2; ++kk)
#pragma unroll
    for (int fj = 0; fj < 4; ++fj) {
      int rk = fj * 16 + li;
      foff[kk][fj] = rk * 64 + (((kk * 4 + g) ^ (rk & 7)) * 8);
    }
  const int lsw = li & 14;
  int pwoff[2][4], proff[2][2];
#pragma unroll
  for (int u = 0; u < 2; ++u) {
#pragma unroll
    for (int fj = 0; fj < 4; ++fj)
      pwoff[u][fj] = (u * 16 + li) * 64 + (((4 * fj + g) ^ lsw) * 4);
#pragma unroll
    for (int kk = 0; kk < 2; ++kk)
      proff[u][kk] = (u * 16 + li) * 64 + (((8 * kk + 2 * g) ^ lsw) * 4);
  }

  auto stage = [&](int buf, int j0) {
    const u16* kp = kbase + (size_t)j0 * 3072;
    const u16* vp = vtb + j0;
    u16* kd = kd0 + buf * 4096;
    u16* vd = vd0 + buf * 4096;
    gload_lds16(kp + kge0, kd);
    gload_lds16(kp + kge0 + 32 * 3072, kd + 2048);
    gload_lds16(vp + vge0, vd);
    gload_lds16(vp + vge0 + 32 * 2048, vd + 2048);
  };

  stage(0, 0);
  __syncthreads();

  s16x8 qf[2][2];
  f32x4 oacc[2][4];
  float mrow[2], lrowp[2];
  int wq0 = 0, qg[2];
  const float cexp = 0.18033688011112042f;   // (1/sqrt(64)) * log2(e)
  const float thr = 8.0f;

  for (int s = 0; s < nTot; ++s) {
    const int cur = s & 1;
    const bool inA = s < nAi;
    const int t  = inA ? s : s - nAi;
    const int qt = inA ? tA : p;
    const int j0 = t * 64;
    const int tLast = inA ? (nAi - 1) : (nTot - nAi - 1);

    if (s + 1 < nTot) {                      // prefetch next tile before compute
      int t1 = (s + 1 < nAi) ? (s + 1) : (s + 1 - nAi);
      stage(cur ^ 1, t1 * 64);
    }

    if (t == 0) {                            // new q-tile: load Q frags, reset state
      wq0 = qt * 128 + w * 32;
#pragma unroll
      for (int u = 0; u < 2; ++u) {
        qg[u] = wq0 + u * 16 + li;
        const u16* qbase = qkv + (size_t)(b * 2048 + qg[u]) * 3072 + h * 64;
#pragma unroll
        for (int kk = 0; kk < 2; ++kk)
          qf[u][kk] = *(const s16x8*)&qbase[kk * 32 + g * 8];
        mrow[u] = -1e30f; lrowp[u] = 0.f;
#pragma unroll
        for (int fd = 0; fd < 4; ++fd) oacc[u][fd] = (f32x4)0.f;
      }
    }

    if (j0 < wq0 + 32) {                     // wave-level causal tile skip
      const u16* ksb = &Ks[0][0] + cur * 4096;
      const u16* vsb = &Vs[0][0] + cur * 4096;

      // S^T = K Q^T  (lane: q = li; kv = fj*16 + g*4 + r)
      f32x4 sfr[2][4] = {};
      __builtin_amdgcn_s_setprio(1);
#pragma unroll
      for (int kk = 0; kk < 2; ++kk) {
        s16x8 kf[4];
#pragma unroll
        for (int fj = 0; fj < 4; ++fj) kf[fj] = *(const s16x8*)&ksb[foff[kk][fj]];
#pragma unroll
        for (int u = 0; u < 2; ++u)
#pragma unroll
          for (int fj = 0; fj < 4; ++fj)
            sfr[u][fj] = mfma_bf16(kf[fj], qf[u][kk], sfr[u][fj]);
      }
      __builtin_amdgcn_s_setprio(0);

      if (j0 + 63 > wq0) {                   // diagonal: causal elem mask
#pragma unroll
        for (int u = 0; u < 2; ++u)
#pragma unroll
          for (int fj = 0; fj < 4; ++fj)
#pragma unroll
            for (int r = 0; r < 4; ++r) {
              int jj = j0 + fj * 16 + g * 4 + r;
              if (jj > qg[u]) sfr[u][fj][r] = -1e30f;
            }
      }

      // lane-local max; cross-lane reduce ONLY when threshold exceeded
      float mx[2];
#pragma unroll
      for (int u = 0; u < 2; ++u) {
        float m0 = sfr[u][0][0];
#pragma unroll
        for (int fj = 0; fj < 4; ++fj)
#pragma unroll
          for (int r = 0; r < 4; ++r) m0 = fmaxf(m0, sfr[u][fj][r]);
        mx[u] = m0;
      }
      bool need = ((mx[0] - mrow[0]) * cexp > thr) | ((mx[1] - mrow[1]) * cexp > thr);
      if (__any(need)) {
#pragma unroll
        for (int u = 0; u < 2; ++u) {
          float m0 = mx[u];
          m0 = fmaxf(m0, __shfl_xor(m0, 16));
          m0 = fmaxf(m0, __shfl_xor(m0, 32));
          float mnew = fmaxf(mrow[u], m0);
          float sc = exp2f((mrow[u] - mnew) * cexp);
          mrow[u] = mnew;
          lrowp[u] *= sc;
#pragma unroll
          for (int fd = 0; fd < 4; ++fd)
#pragma unroll
            for (int r = 0; r < 4; ++r) oacc[u][fd][r] *= sc;
        }
      }

      // exp (bounded by 2^thr), per-lane partial sum, pack P to LDS
#pragma unroll
      for (int u = 0; u < 2; ++u) {
        float rs = 0.f;
#pragma unroll
        for (int fj = 0; fj < 4; ++fj) {
          float p0 = exp2f((sfr[u][fj][0] - mrow[u]) * cexp);
          float p1 = exp2f((sfr[u][fj][1] - mrow[u]) * cexp);
          float p2 = exp2f((sfr[u][fj][2] - mrow[u]) * cexp);
          float p3 = exp2f((sfr[u][fj][3] - mrow[u]) * cexp);
          rs += (p0 + p1) + (p2 + p3);
          u32x2 wv = { cvtpk(p0, p1), cvtpk(p2, p3) };
          *(u32x2*)&pl[pwoff[u][fj]] = wv;
        }
        lrowp[u] += rs;                      // per-lane partial; no shfl here
      }

      // O^T += V^T P^T
      __builtin_amdgcn_s_setprio(1);
#pragma unroll
      for (int kk = 0; kk < 2; ++kk) {
        s16x8 vf[4];
#pragma unroll
        for (int fd = 0; fd < 4; ++fd) vf[fd] = *(const s16x8*)&vsb[foff[kk][fd]];
#pragma unroll
        for (int u = 0; u < 2; ++u) {
          s16x8 pf = *(const s16x8*)&pl[proff[u][kk]];
#pragma unroll
          for (int fd = 0; fd < 4; ++fd)
            oacc[u][fd] = mfma_bf16(vf[fd], pf, oacc[u][fd]);
        }
      }
      __builtin_amdgcn_s_setprio(0);
    }

    if (t == tLast) {                        // q-tile done: reduce l, write out
#pragma unroll
      for (int u = 0; u < 2; ++u) {
        float lr = lrowp[u];
        lr += __shfl_xor(lr, 16);
        lr += __shfl_xor(lr, 32);
        float inv = 1.f / lr;
        u16* ob = out + (size_t)(b * 2048 + qg[u]) * 1024 + h * 64;
#pragma unroll
        for (int fd = 0; fd < 4; ++fd) {
          u32x2 wv = { cvtpk(oacc[u][fd][0] * inv, oacc[u][fd][1] * inv),
                       cvtpk(oacc[u][fd][2] * inv, oacc[u][fd][3] * inv) };
          *(u32x2*)&ob[fd * 16 + g * 4] = wv;
        }
      }
    }

    __syncthreads();                         // drains prefetch; buf swap safe
  }
}

// --- launch ------------------------------------------------------------------

extern "C" void kernel_launch(void* const* d_in, const int* in_sizes, int n_in,
                              void* d_out, int out_size, void* d_ws, size_t ws_size,
                              hipStream_t stream) {
  const float* x  = (const float*)d_in[0];
  const float* Wq = (const float*)d_in[1];
  const float* Wk = (const float*)d_in[2];
  const float* Wv = (const float*)d_in[3];
  const float* Wp = (const float*)d_in[4];
  const float* bp = (const float*)d_in[5];
  (void)in_sizes; (void)n_in; (void)out_size; (void)ws_size;

  char* ws = (char*)d_ws;
  u16* xb    = (u16*)(ws);                   // [8192][1024]  16 MB
  u16* wqkvb = (u16*)(ws + 16777216);        // [3072][1024]   6 MB
  u16* wpb   = (u16*)(ws + 23068672);        // [1024][1024]   2 MB
  u16* qkv   = (u16*)(ws + 25165824);        // [8192][3072]  48 MB (v third unused)
  u16* vT    = (u16*)(ws + 75497472);        // [64][64][2048] 16 MB
  u16* ao    = (u16*)(ws + 92274688);        // [8192][1024]  16 MB

  cvt_f32_bf16_kernel<<<4096, 256, 0, stream>>>(x, xb);
  cvt_wqkv_kernel<<<12288, 256, 0, stream>>>(Wq, Wk, Wv, wqkvb);
  cvt_f32_bf16_kernel<<<512, 256, 0, stream>>>(Wp, wpb);

  gemm_bt_kernel<2><<<dim3(64, 24), 256, 0, stream>>>(
      xb, wqkvb, (void*)qkv, nullptr, vT, 1024, 3072);

  attn_kernel<<<512, 256, 0, stream>>>(qkv, vT, ao);

  gemm_bt_kernel<1><<<dim3(64, 8), 256, 0, stream>>>(
      ao, wpb, d_out, bp, nullptr, 1024, 1024);
}

// Round 6
// 171.614 us; speedup vs baseline: 1.9640x; 1.0177x over previous
//
#include <hip/hip_runtime.h>
#include <stdint.h>

// ---------------------------------------------------------------------------
// MultiHeadAttention B=4 T=2048 C=1024 H=16 D=64  (fp32 in/out, causal)
// Pipeline: cvt(bf16) -> GEMM(QKV, v written transposed) -> flash-attn -> GEMM(proj)+bias
// ---------------------------------------------------------------------------

typedef unsigned short u16;
typedef __attribute__((ext_vector_type(8))) short    s16x8;
typedef __attribute__((ext_vector_type(4))) float    f32x4;
typedef __attribute__((ext_vector_type(2))) uint32_t u32x2;

// --- helpers ---------------------------------------------------------------

__device__ __forceinline__ u16 f2b(float f) {  // f32 -> bf16 RNE
  union { float f; uint32_t u; } v; v.f = f;
  uint32_t r = v.u + 0x7FFFu + ((v.u >> 16) & 1u);
  return (u16)(r >> 16);
}

__device__ __forceinline__ uint32_t cvtpk(float a, float b) {  // [lo=bf16(a), hi=bf16(b)]
  uint32_t r;
  asm("v_cvt_pk_bf16_f32 %0, %1, %2" : "=v"(r) : "v"(a), "v"(b));
  return r;
}

// v_mfma_f32_16x16x32_bf16. A: lane holds A[m=l&15][8k contig]; B: B^T[n=l&15][8k contig]
// C/D: row=(l>>4)*4+reg, col=l&15
__device__ __forceinline__ f32x4 mfma_bf16(s16x8 a, s16x8 b, f32x4 c) {
  asm("v_mfma_f32_16x16x32_bf16 %0, %1, %2, %0" : "+v"(c) : "v"(a), "v"(b));
  return c;
}

// async global->LDS, 16B per lane. LDS dest is wave-uniform base + lane*16.
__device__ __forceinline__ void gload_lds16(const void* g, void* l) {
  __builtin_amdgcn_global_load_lds(
      (__attribute__((address_space(1))) void*)(uintptr_t)g,
      (__attribute__((address_space(3))) void*)(uint32_t)(uintptr_t)l,
      16, 0, 0);
}

// --- conversion kernels ------------------------------------------------------

__global__ void cvt_f32_bf16_kernel(const float* __restrict__ in, u16* __restrict__ out) {
  size_t i = (size_t)blockIdx.x * 256 + threadIdx.x;
  const f32x4* p = (const f32x4*)(in + i * 8);
  f32x4 a = p[0], b = p[1];
  s16x8 o;
  o[0]=(short)f2b(a[0]); o[1]=(short)f2b(a[1]); o[2]=(short)f2b(a[2]); o[3]=(short)f2b(a[3]);
  o[4]=(short)f2b(b[0]); o[5]=(short)f2b(b[1]); o[6]=(short)f2b(b[2]); o[7]=(short)f2b(b[3]);
  *(s16x8*)(out + i * 8) = o;
}

// Wq/Wk/Wv [H,C,D] f32 -> wqkvb [3*H*D][C] bf16  (B^T layout for the GEMM)
__global__ void cvt_wqkv_kernel(const float* __restrict__ Wq, const float* __restrict__ Wk,
                                const float* __restrict__ Wv, u16* __restrict__ out) {
  int idx = blockIdx.x * 256 + threadIdx.x;
  int sel = idx >> 20;
  int rem = idx & 1048575;
  int n = rem >> 10, c = rem & 1023;
  int h = n >> 6, d = n & 63;
  const float* W = (sel == 0) ? Wq : ((sel == 1) ? Wk : Wv);
  out[idx] = f2b(W[h * 65536 + c * 64 + d]);
}

// --- GEMM: C[M][N] = A[M][K] * B[N][K]^T  (bf16 in, 128x128 tile, BK=64) ----
// MODE 1: f32 out + bias.  MODE 2: qkv: cols<2048 -> bf16 C; v cols -> vT transposed.

template <int MODE>
__global__ __launch_bounds__(256) void gemm_bt_kernel(
    const u16* __restrict__ A, const u16* __restrict__ B, void* __restrict__ Cout,
    const float* __restrict__ bias, u16* __restrict__ vTout, int K, int ldc)
{
  __shared__ __attribute__((aligned(16))) u16 As[128 * 64];
  __shared__ __attribute__((aligned(16))) u16 Bs[128 * 64];

  const int tid  = threadIdx.x;
  const int lane = tid & 63;
  const int w    = tid >> 6;
  const int wm   = w >> 1, wn = w & 1;
  const int g    = lane >> 4;
  const int li   = lane & 15;
  const size_t bm = (size_t)blockIdx.x * 128;
  const size_t bn = (size_t)blockIdx.y * 128;

  f32x4 acc[4][4] = {};

  const int kIters = K >> 6;
  for (int kt = 0; kt < kIters; ++kt) {
    const int kb = kt * 64;
#pragma unroll
    for (int i = 0; i < 4; ++i) {
      int c = i * 256 + tid;
      int row = c >> 3, sl = c & 7;
      int ss = sl ^ (row & 7);
      gload_lds16(A + (bm + row) * K + kb + ss * 8, &As[c * 8]);
      gload_lds16(B + (bn + row) * K + kb + ss * 8, &Bs[c * 8]);
    }
    __syncthreads();
#pragma unroll
    for (int ks = 0; ks < 2; ++ks) {
      s16x8 af[4], bfr[4];
#pragma unroll
      for (int f = 0; f < 4; ++f) {
        int ra = wm * 64 + f * 16 + li;
        int sa = (ks * 4 + g) ^ (ra & 7);
        af[f] = *(const s16x8*)&As[ra * 64 + sa * 8];
        int rb = wn * 64 + f * 16 + li;
        int sb = (ks * 4 + g) ^ (rb & 7);
        bfr[f] = *(const s16x8*)&Bs[rb * 64 + sb * 8];
      }
#pragma unroll
      for (int mi = 0; mi < 4; ++mi)
#pragma unroll
        for (int ni = 0; ni < 4; ++ni)
          acc[mi][ni] = mfma_bf16(af[mi], bfr[ni], acc[mi][ni]);
    }
    __syncthreads();
  }

  if constexpr (MODE == 1) {
#pragma unroll
    for (int ni = 0; ni < 4; ++ni) {
      size_t col = bn + wn * 64 + ni * 16 + li;
      float bv = bias[col];
#pragma unroll
      for (int mi = 0; mi < 4; ++mi)
#pragma unroll
        for (int r = 0; r < 4; ++r) {
          size_t row = bm + wm * 64 + mi * 16 + g * 4 + r;
          ((float*)Cout)[row * ldc + col] = acc[mi][ni][r] + bv;
        }
    }
  } else {
    if (bn < 2048) {                 // q|k region: bf16 into qkv
#pragma unroll
      for (int ni = 0; ni < 4; ++ni) {
        size_t col = bn + wn * 64 + ni * 16 + li;
#pragma unroll
        for (int mi = 0; mi < 4; ++mi)
#pragma unroll
          for (int r = 0; r < 4; ++r) {
            size_t row = bm + wm * 64 + mi * 16 + g * 4 + r;
            ((u16*)Cout)[row * ldc + col] = f2b(acc[mi][ni][r]);
          }
      }
    } else {                         // v region: write transposed into vT[bh][d][t]
      const int hb = (int)((bn - 2048) >> 6) + wn;
      const int bb = (int)(bm >> 11);
      const int t0b = ((int)bm & 2047) + wm * 64 + g * 4;
      u16* vrow = vTout + (size_t)((bb * 16 + hb) * 64) * 2048;
#pragma unroll
      for (int ni = 0; ni < 4; ++ni) {
        u16* vd_ = vrow + (size_t)(ni * 16 + li) * 2048;
#pragma unroll
        for (int mi = 0; mi < 4; ++mi) {
          u32x2 wv = { cvtpk(acc[mi][ni][0], acc[mi][ni][1]),
                       cvtpk(acc[mi][ni][2], acc[mi][ni][3]) };
          *(u32x2*)&vd_[t0b + mi * 16] = wv;
        }
      }
    }
  }
}

// --- flash attention (causal) v6 ---------------------------------------------
// v4 occupancy (QBLK=64, 1024 blocks, 40KB LDS -> 4 blocks/CU = 4 waves/SIMD)
// + v5 chain-shortening (per-lane lrow partials; __any-gated max-reduce ->
// zero cross-lane ops on the common path). Causal pairing p=0..15:
// q-tiles (31-p) then (p), 33 kv-iters per block. Double-buffered K/V,
// prefetch-before-compute. Lane-local softmax (q = lane&15).

__global__ __launch_bounds__(256, 4) void attn_kernel(const u16* __restrict__ qkv,
                                                      const u16* __restrict__ vT,
                                                      u16* __restrict__ out) {
  __shared__ __attribute__((aligned(16))) u16 Ks[2][64 * 64];
  __shared__ __attribute__((aligned(16))) u16 Vs[2][64 * 64];
  __shared__ __attribute__((aligned(16))) u16 Ps[4][16 * 64];

  const int id  = blockIdx.x;                // 1024 blocks
  const int xcd = id & 7;
  const int rr  = id >> 3;
  const int bh  = xcd * 8 + (rr & 7);        // 8 bh per XCD
  const int p   = rr >> 3;                   // 0..15

  const int b = bh >> 4, h = bh & 15;
  const int tid = threadIdx.x;
  const int lane = tid & 63;
  const int w = tid >> 6;
  const int g = lane >> 4, li = lane & 15;

  const int tA = 31 - p;
  const int nA = tA + 1;
  const int nTot = 33;                       // nA + p + 1

  const u16* kbase = qkv + (size_t)(b * 2048) * 3072 + 1024 + h * 64;
  const u16* vtb   = vT + (size_t)bh * 64 * 2048;
  u16* pl = Ps[w];

  // hoisted per-lane offsets
  const int srow = tid >> 3;
  const int ssl0 = (tid & 7) ^ (srow & 7);
  const int kge0 = srow * 3072 + ssl0 * 8;
  const int vge0 = srow * 2048 + ssl0 * 8;
  u16* const kd0 = &Ks[0][tid * 8];
  u16* const vd0 = &Vs[0][tid * 8];

  int foff[2][4];                            // kf/vf fragment offsets
#pragma unroll
  for (int kk = 0; kk < 2; ++kk)
#pragma unroll
    for (int fj = 0; fj < 4; ++fj) {
      int rk = fj * 16 + li;
      foff[kk][fj] = rk * 64 + (((kk * 4 + g) ^ (rk & 7)) * 8);
    }
  const int lsw = li & 14;
  int pwoff[4], proff[2];
#pragma unroll
  for (int fj = 0; fj < 4; ++fj) pwoff[fj] = li * 64 + (((4 * fj + g) ^ lsw) * 4);
#pragma unroll
  for (int kk = 0; kk < 2; ++kk) proff[kk] = li * 64 + (((8 * kk + 2 * g) ^ lsw) * 4);

  auto stage = [&](int buf, int j0) {
    const u16* kp = kbase + (size_t)j0 * 3072;
    const u16* vp = vtb + j0;
    u16* kd = kd0 + buf * 4096;
    u16* vd = vd0 + buf * 4096;
    gload_lds16(kp + kge0, kd);
    gload_lds16(kp + kge0 + 32 * 3072, kd + 2048);
    gload_lds16(vp + vge0, vd);
    gload_lds16(vp + vge0 + 32 * 2048, vd + 2048);
  };

  stage(0, 0);
  __syncthreads();

  s16x8 qf[2];
  f32x4 oacc[4];
  float mrow = -1e30f, lrowp = 0.f;
  int qglob = 0;
  const float cexp = 0.18033688011112042f;   // (1/sqrt(64)) * log2(e)
  const float thr = 8.0f;

  for (int s = 0; s < nTot; ++s) {
    const int cur = s & 1;
    const bool inA = s < nA;
    const int t  = inA ? s : s - nA;
    const int qt = inA ? tA : p;
    const int j0 = t * 64;

    if (s + 1 < nTot) {                      // prefetch next tile before compute
      int t1 = (s + 1 < nA) ? (s + 1) : (s + 1 - nA);
      stage(cur ^ 1, t1 * 64);
    }

    if (t == 0) {                            // new q-tile: load Q frags, reset state
      qglob = qt * 64 + w * 16 + li;
      const u16* qbase = qkv + (size_t)(b * 2048 + qglob) * 3072 + h * 64;
#pragma unroll
      for (int kk = 0; kk < 2; ++kk)
        qf[kk] = *(const s16x8*)&qbase[kk * 32 + g * 8];
      mrow = -1e30f; lrowp = 0.f;
#pragma unroll
      for (int fd = 0; fd < 4; ++fd) oacc[fd] = (f32x4)0.f;
    }

    const u16* ksb = &Ks[0][0] + cur * 4096;
    const u16* vsb = &Vs[0][0] + cur * 4096;

    // S^T = K Q^T  (lane: q = li fixed; kv = fj*16 + g*4 + r)
    f32x4 sfr[4] = {};
    __builtin_amdgcn_s_setprio(1);
#pragma unroll
    for (int kk = 0; kk < 2; ++kk) {
      s16x8 kf[4];
#pragma unroll
      for (int fj = 0; fj < 4; ++fj) kf[fj] = *(const s16x8*)&ksb[foff[kk][fj]];
#pragma unroll
      for (int fj = 0; fj < 4; ++fj) sfr[fj] = mfma_bf16(kf[fj], qf[kk], sfr[fj]);
    }
    __builtin_amdgcn_s_setprio(0);

    if (t == qt) {                           // diagonal tile: causal elem mask
#pragma unroll
      for (int fj = 0; fj < 4; ++fj)
#pragma unroll
        for (int r = 0; r < 4; ++r) {
          int jj = j0 + fj * 16 + g * 4 + r;
          if (jj > qglob) sfr[fj][r] = -1e30f;
        }
    }

    // lane-local max; cross-lane reduce ONLY when threshold exceeded (T13 ext)
    float mx = sfr[0][0];
#pragma unroll
    for (int fj = 0; fj < 4; ++fj)
#pragma unroll
      for (int r = 0; r < 4; ++r) mx = fmaxf(mx, sfr[fj][r]);

    bool need = (mx - mrow) * cexp > thr;
    if (__any(need)) {
      float m0 = mx;
      m0 = fmaxf(m0, __shfl_xor(m0, 16));
      m0 = fmaxf(m0, __shfl_xor(m0, 32));
      float mnew = fmaxf(mrow, m0);
      float sc = exp2f((mrow - mnew) * cexp);
      mrow = mnew;
      lrowp *= sc;
#pragma unroll
      for (int fd = 0; fd < 4; ++fd)
#pragma unroll
        for (int r = 0; r < 4; ++r) oacc[fd][r] *= sc;
    }

    // exp (bounded by 2^thr), per-lane partial sum, pack P to LDS
    float rs = 0.f;
#pragma unroll
    for (int fj = 0; fj < 4; ++fj) {
      float p0 = exp2f((sfr[fj][0] - mrow) * cexp);
      float p1 = exp2f((sfr[fj][1] - mrow) * cexp);
      float p2 = exp2f((sfr[fj][2] - mrow) * cexp);
      float p3 = exp2f((sfr[fj][3] - mrow) * cexp);
      rs += (p0 + p1) + (p2 + p3);
      u32x2 wv = { cvtpk(p0, p1), cvtpk(p2, p3) };
      *(u32x2*)&pl[pwoff[fj]] = wv;
    }
    lrowp += rs;                             // per-lane partial; no shfl here

    // O^T += V^T P^T
    __builtin_amdgcn_s_setprio(1);
#pragma unroll
    for (int kk = 0; kk < 2; ++kk) {
      s16x8 pf = *(const s16x8*)&pl[proff[kk]];
      s16x8 vf[4];
#pragma unroll
      for (int fd = 0; fd < 4; ++fd) vf[fd] = *(const s16x8*)&vsb[foff[kk][fd]];
#pragma unroll
      for (int fd = 0; fd < 4; ++fd) oacc[fd] = mfma_bf16(vf[fd], pf, oacc[fd]);
    }
    __builtin_amdgcn_s_setprio(0);

    if (t == qt) {                           // q-tile done: reduce l, write out
      float lr = lrowp;
      lr += __shfl_xor(lr, 16);
      lr += __shfl_xor(lr, 32);
      float inv = 1.f / lr;
      u16* ob = out + (size_t)(b * 2048 + qglob) * 1024 + h * 64;
#pragma unroll
      for (int fd = 0; fd < 4; ++fd) {
        u32x2 wv = { cvtpk(oacc[fd][0] * inv, oacc[fd][1] * inv),
                     cvtpk(oacc[fd][2] * inv, oacc[fd][3] * inv) };
        *(u32x2*)&ob[fd * 16 + g * 4] = wv;
      }
    }

    __syncthreads();                         // drains prefetch; buf swap safe
  }
}

// --- launch ------------------------------------------------------------------

extern "C" void kernel_launch(void* const* d_in, const int* in_sizes, int n_in,
                              void* d_out, int out_size, void* d_ws, size_t ws_size,
                              hipStream_t stream) {
  const float* x  = (const float*)d_in[0];
  const float* Wq = (const float*)d_in[1];
  const float* Wk = (const float*)d_in[2];
  const float* Wv = (const float*)d_in[3];
  const float* Wp = (const float*)d_in[4];
  const float* bp = (const float*)d_in[5];
  (void)in_sizes; (void)n_in; (void)out_size; (void)ws_size;

  char* ws = (char*)d_ws;
  u16* xb    = (u16*)(ws);                   // [8192][1024]  16 MB
  u16* wqkvb = (u16*)(ws + 16777216);        // [3072][1024]   6 MB
  u16* wpb   = (u16*)(ws + 23068672);        // [1024][1024]   2 MB
  u16* qkv   = (u16*)(ws + 25165824);        // [8192][3072]  48 MB (v third unused)
  u16* vT    = (u16*)(ws + 75497472);        // [64][64][2048] 16 MB
  u16* ao    = (u16*)(ws + 92274688);        // [8192][1024]  16 MB

  cvt_f32_bf16_kernel<<<4096, 256, 0, stream>>>(x, xb);
  cvt_wqkv_kernel<<<12288, 256, 0, stream>>>(Wq, Wk, Wv, wqkvb);
  cvt_f32_bf16_kernel<<<512, 256, 0, stream>>>(Wp, wpb);

  gemm_bt_kernel<2><<<dim3(64, 24), 256, 0, stream>>>(
      xb, wqkvb, (void*)qkv, nullptr, vT, 1024, 3072);

  attn_kernel<<<1024, 256, 0, stream>>>(qkv, vT, ao);

  gemm_bt_kernel<1><<<dim3(64, 8), 256, 0, stream>>>(
      ao, wpb, d_out, bp, nullptr, 1024, 1024);
}